// Round 2
// baseline (4453.049 us; speedup 1.0000x reference)
//
#include <hip/hip_runtime.h>
#include <math.h>

#define B_SZ 64
#define WID 128
#define NPT 4096
#define MODES 128
#define LSEG 20
#define MCH 8
#define LM 160   // LSEG*MCH

// ---------------- workspace layout (floats), total ~169.3 MB ----------------
static constexpr size_t o_h    = 0;                                    // [64][128][4096]
static constexpr size_t o_Tf   = o_h  + (size_t)B_SZ*WID*NPT;          // fwd table [4096][256]
static constexpr size_t o_Ti   = o_Tf + (size_t)NPT*256;               // inv table [256][4096]
static constexpr size_t o_Wcre = o_Ti + (size_t)256*NPT;               // [160][128]
static constexpr size_t o_Wcim = o_Wcre + LM*MODES;
static constexpr size_t o_wl   = o_Wcim + LM*MODES;                    // [160]
static constexpr size_t o_wr   = o_wl + 256;
static constexpr size_t o_li   = o_wr + 256;                           // int[160]
static constexpr size_t o_wsum = o_li + 256;                           // [4 tensors][4 layers][128][128]
static constexpr size_t o_F    = o_wsum + 4*4*16384;                   // [8192][256]
static constexpr size_t o_X    = o_F + (size_t)8192*256;               // [8192][256]
static constexpr size_t o_Wg   = o_X + (size_t)8192*256;               // [64][2][128][128]
static constexpr size_t o_magp = o_Wg + (size_t)B_SZ*2*16384;          // [64][8][128]
static constexpr size_t o_gate = o_magp + B_SZ*8*128;                  // [64][128]
static constexpr size_t o_end  = o_gate + B_SZ*128;

__device__ __forceinline__ float gelu_f(float x){
    return 0.5f*x*(1.0f+erff(x*0.70710678118654752f));
}

// ---------------- tables ----------------
__global__ void k_dft_tables(float* __restrict__ Tf, float* __restrict__ Ti){
    int idx = blockIdx.x*256 + threadIdx.x;   // 4096*256
    int n = idx >> 8, k2 = idx & 255;
    int f = k2 >> 1;
    int m = (n*f) & 4095;
    double th = (double)m * (3.14159265358979323846/2048.0);
    double s, c; sincos(th, &s, &c);
    Tf[n*256 + k2] = (k2&1) ? (float)(-s) : (float)c;
    float inv;
    if (k2 == 0)      inv = 1.0f/4096.0f;
    else if (k2 == 1) inv = 0.0f;             // Im(X[0]) ignored by irfft
    else              inv = ((k2&1)? (float)(-s) : (float)c) * (2.0f/4096.0f);
    Ti[(size_t)k2*4096 + n] = inv;
}

__global__ void k_cft_tables(float* __restrict__ Wre, float* __restrict__ Wim,
                             float* __restrict__ wl, float* __restrict__ wr,
                             int* __restrict__ li){
    int idx = blockIdx.x*128 + threadIdx.x;   // 160*128
    if (idx >= LM*MODES) return;
    int lm = idx >> 7;  int f = idx & 127;
    int l = lm / MCH, m = lm % MCH;
    const double PI = 3.14159265358979323846;
    double nodes[8], Tm[8];
    #pragma unroll
    for (int j=0;j<8;j++){
        nodes[j] = -cos((2.0*j+1.0)*PI/16.0);
        Tm[j] = cos((double)m * acos(nodes[j]));
    }
    double wp = (double)f * PI * 0.05;        // f * 2*pi*seg_len/2
    double cwre=0.0, cwim=0.0;
    #pragma unroll
    for (int j=0;j<8;j++){
        double sj, cj; sincos(nodes[j]*wp, &sj, &cj);
        cwre += Tm[j]*cj;
        cwim -= Tm[j]*sj;
    }
    cwre *= 0.025; cwim *= 0.025;             // * seg_len/2
    int r = (f*l) % 20;
    double sa = 2.0*PI*(double)r/20.0;        // shift = exp(-i*2pi*f*a_l)
    double shre = cos(sa), shim = -sin(sa);
    Wre[lm*128+f] = (float)(shre*cwre - shim*cwim);
    Wim[lm*128+f] = (float)(shre*cwim + shim*cwre);
    if (f == 0){
        double v = (double)l/20.0 + 0.025*(nodes[m]+1.0);
        int rr = (int)ceil(v*4095.0);
        if (rr > 4095) rr = 4095;
        if (rr < 1) rr = 1;
        int le = rr-1;
        double tl = (double)le/4095.0, tr = (double)rr/4095.0;
        double wrv = (v - tl)/(tr - tl);
        li[lm] = le;
        wl[lm] = (float)(1.0 - wrv);
        wr[lm] = (float)wrv;
    }
}

// sum wA/wB over mode axis: rows of 128 contiguous floats
__global__ void k_wsum(const float* __restrict__ wAre, const float* __restrict__ wAim,
                       const float* __restrict__ wBre, const float* __restrict__ wBim,
                       float* __restrict__ out){
    int row  = blockIdx.x*4 + (threadIdx.x>>6);    // 65536 rows per tensor
    int lane = threadIdx.x & 63;
    const float* src = (blockIdx.y==0)?wAre:(blockIdx.y==1)?wAim:(blockIdx.y==2)?wBre:wBim;
    float v = src[(size_t)row*128 + lane] + src[(size_t)row*128 + 64 + lane];
    #pragma unroll
    for (int o=32;o>0;o>>=1) v += __shfl_down(v, o);
    if (lane==0) out[(size_t)blockIdx.y*65536 + row] = v;
}

// ---------------- lift: h0[b][w][n] ----------------
__global__ void k_h0(const float* __restrict__ x, const float* __restrict__ w0,
                     const float* __restrict__ b0, float* __restrict__ h){
    size_t idx = (size_t)blockIdx.x*256 + threadIdx.x;  // B*W*N
    int n = idx & 4095;
    int w = (idx >> 12) & 127;
    int b = idx >> 19;
    float g = (float)n * (1.0f/4095.0f);
    h[idx] = x[((size_t)b<<12) + n]*w0[w*2] + g*w0[w*2+1] + b0[w];
}

// ---------------- CFT magnitude (partial over 16-channel groups) ----------------
__global__ void k_cft(const float* __restrict__ h, const float* __restrict__ Wre,
                      const float* __restrict__ Wim, const float* __restrict__ wl,
                      const float* __restrict__ wr, const int* __restrict__ li,
                      float* __restrict__ magp){
    int b = blockIdx.x, cg = blockIdx.y;
    int f = threadIdx.x;   // 128
    __shared__ float sig[LM];
    __shared__ float swl[LM], swr[LM];
    __shared__ int   sli[LM];
    for (int s=f; s<LM; s+=128){ swl[s]=wl[s]; swr[s]=wr[s]; sli[s]=li[s]; }
    __syncthreads();
    float acc = 0.f;
    for (int cc=0; cc<16; cc++){
        int c = cg*16 + cc;
        const float* hr = h + ((size_t)(b*128+c))*4096;
        for (int s=f; s<LM; s+=128){
            int le = sli[s];
            sig[s] = swl[s]*hr[le] + swr[s]*hr[le+1];
        }
        __syncthreads();
        float re=0.f, im=0.f;
        #pragma unroll 8
        for (int s=0;s<LM;s++){
            float sv = sig[s];
            re = fmaf(sv, Wre[s*128+f], re);
            im = fmaf(sv, Wim[s*128+f], im);
        }
        acc += sqrtf(re*re+im*im);
        __syncthreads();
    }
    magp[(b*8+cg)*128 + f] = acc;
}

// gate[b][w] = sigmoid(sum_f mean_mag[b][f]*gW[layer][w][f] + gb[layer][w])
__global__ void k_gate(const float* __restrict__ magp, const float* __restrict__ gW,
                       const float* __restrict__ gB, float* __restrict__ gate, int layer){
    int b = blockIdx.x, w = threadIdx.x;
    __shared__ float ms[128];
    float s = 0.f;
    #pragma unroll
    for (int g=0; g<8; g++) s += magp[(b*8+g)*128 + w];
    ms[w] = s * (1.0f/128.0f);
    __syncthreads();
    const float* gwr = gW + ((size_t)layer*128 + w)*128;
    float a = gB[layer*128 + w];
    #pragma unroll 8
    for (int fq=0; fq<128; fq++) a = fmaf(ms[fq], gwr[fq], a);
    gate[b*128+w] = 1.0f/(1.0f+expf(-a));
}

// Wg[b][re/im][in][o] = g[b,o]*wA_sum + (1-g)*wB_sum
__global__ void k_wg(const float* __restrict__ wsum, const float* __restrict__ gate,
                     float* __restrict__ Wg, int layer){
    int idx = blockIdx.x*256 + threadIdx.x;  // 64*128*128
    int o = idx & 127, in = (idx>>7)&127, b = idx>>14;
    float g = gate[b*128+o];
    int e = in*128+o;
    size_t lo = (size_t)layer*16384 + e;
    float are = wsum[0*65536 + lo], aim = wsum[1*65536 + lo];
    float bre = wsum[2*65536 + lo], bim = wsum[3*65536 + lo];
    Wg[((size_t)(b*2+0))*16384 + e] = g*are + (1.f-g)*bre;
    Wg[((size_t)(b*2+1))*16384 + e] = g*aim + (1.f-g)*bim;
}

// ---------------- forward DFT as GEMM: C[8192][256] = h[8192][4096] * Tf[4096][256]
#define BM 64
#define BN 64
#define BK 32
__global__ __launch_bounds__(256) void k_dft(const float* __restrict__ A,
                                             const float* __restrict__ Bm,
                                             float* __restrict__ C){
    __shared__ float As[BK][BM+4];
    __shared__ float Bs[BK][BN+4];
    int row0 = blockIdx.y*BM, col0 = blockIdx.x*BN;
    int tid = threadIdx.x;
    int tx = tid & 15, ty = tid >> 4;
    float acc[4][4] = {};
    for (int k0=0; k0<4096; k0+=BK){
        {
            int k = tid & 31, r = tid >> 5;
            #pragma unroll
            for (int p=0;p<8;p++){
                int m = p*8 + r;
                As[k][m] = A[(size_t)(row0+m)*4096 + k0 + k];
            }
        }
        {
            int n = tid & 63, kk = tid >> 6;
            #pragma unroll
            for (int p=0;p<8;p++){
                int k = p*4 + kk;
                Bs[k][n] = Bm[(size_t)(k0+k)*256 + col0 + n];
            }
        }
        __syncthreads();
        #pragma unroll
        for (int k=0;k<BK;k++){
            float4 a  = *reinterpret_cast<const float4*>(&As[k][ty*4]);
            float4 bv = *reinterpret_cast<const float4*>(&Bs[k][tx*4]);
            float av[4]={a.x,a.y,a.z,a.w}, bb[4]={bv.x,bv.y,bv.z,bv.w};
            #pragma unroll
            for (int i=0;i<4;i++)
                #pragma unroll
                for (int j=0;j<4;j++) acc[i][j] = fmaf(av[i], bb[j], acc[i][j]);
        }
        __syncthreads();
    }
    #pragma unroll
    for (int i=0;i<4;i++){
        int m = row0 + ty*4 + i;
        #pragma unroll
        for (int j=0;j<4;j++) C[(size_t)m*256 + col0 + tx*4 + j] = acc[i][j];
    }
}

// ---------------- per-batch complex mode mix: X[b][o][2f] = sum_i F[b][i][2f]*Wg[b][i][o]
__global__ __launch_bounds__(256) void k_modemix(const float* __restrict__ F,
                                                 const float* __restrict__ Wg,
                                                 float* __restrict__ X){
    int b = blockIdx.x, og = blockIdx.y;       // 16 groups of 8 o
    __shared__ float Fs[16][256];
    int tid = threadIdx.x;
    int f = tid & 127, half = tid >> 7;
    float accre[4]={}, accim[4]={};
    const float* wgre = Wg + ((size_t)(b*2+0))*16384;
    const float* wgim = Wg + ((size_t)(b*2+1))*16384;
    for (int i0=0;i0<128;i0+=16){
        for (int e=tid; e<16*256; e+=256){
            int ii = e >> 8, k2 = e & 255;
            Fs[ii][k2] = F[((size_t)(b*128 + i0+ii))*256 + k2];
        }
        __syncthreads();
        #pragma unroll
        for (int ii=0; ii<16; ii++){
            float fre = Fs[ii][2*f], fim = Fs[ii][2*f+1];
            int i = i0+ii;
            #pragma unroll
            for (int q=0;q<4;q++){
                int o = og*8 + half*4 + q;
                float wre_ = wgre[i*128+o], wim_ = wgim[i*128+o];
                accre[q] = fmaf(fre, wre_, fmaf(-fim, wim_, accre[q]));
                accim[q] = fmaf(fre, wim_, fmaf( fim, wre_, accim[q]));
            }
        }
        __syncthreads();
    }
    #pragma unroll
    for (int q=0;q<4;q++){
        int o = og*8 + half*4 + q;
        size_t rowX = (size_t)(b*128+o)*256;
        X[rowX + 2*f]   = accre[q];
        X[rowX + 2*f+1] = accim[q];
    }
}

// ---------------- fused IN-PLACE irfft + conv + bias + gelu ----------------
// h[b][o][n] <- gelu( sum_k2 X[b][o][k2]*Ti[k2][n] + sum_c cw[o][c]*h_in[b][c][n] + cb[o] )
// One block owns (b, 64-wide n-tile), computes ALL 128 output channels; h_in
// columns are staged to LDS before any global write -> in-place safe.
__global__ __launch_bounds__(256) void k_layer(
    const float* __restrict__ X, const float* __restrict__ Ti,
    const float* __restrict__ convW, const float* __restrict__ convB,
    float* __restrict__ h, int layer, int applyGelu){
    __shared__ float hblk[128][68];
    __shared__ float at[32][132];
    __shared__ float bt[32][68];
    int n0 = blockIdx.x*64;
    int b  = blockIdx.y;
    int tid = threadIdx.x;
    int tx = tid & 15, ty = tid >> 4;
    // stage own column block [128 c][64 n] into LDS
    #pragma unroll
    for (int p=0;p<8;p++){
        int c = p*16 + ty;
        *reinterpret_cast<float4*>(&hblk[c][tx*4]) =
            *reinterpret_cast<const float4*>(&h[((size_t)(b*128+c))*4096 + n0 + tx*4]);
    }
    float acc[8][4] = {};
    // phase 1: pointwise conv, K=128, A=convW[o][k], B=hblk[k][n]
    const float* cw = convW + (size_t)layer*16384;
    for (int k0=0;k0<128;k0+=32){
        __syncthreads();
        #pragma unroll
        for (int p=0;p<16;p++){
            int e = p*256 + tid;     // 4096 = 32k x 128o
            int o = e >> 5, k = e & 31;
            at[k][o] = cw[(size_t)o*128 + k0 + k];
        }
        __syncthreads();
        #pragma unroll
        for (int k=0;k<32;k++){
            float4 b4 = *reinterpret_cast<const float4*>(&hblk[k0+k][tx*4]);
            float4 a0 = *reinterpret_cast<const float4*>(&at[k][ty*8]);
            float4 a1 = *reinterpret_cast<const float4*>(&at[k][ty*8+4]);
            float av[8]={a0.x,a0.y,a0.z,a0.w,a1.x,a1.y,a1.z,a1.w};
            float bv[4]={b4.x,b4.y,b4.z,b4.w};
            #pragma unroll
            for (int i=0;i<8;i++)
                #pragma unroll
                for (int j=0;j<4;j++) acc[i][j] = fmaf(av[i], bv[j], acc[i][j]);
        }
    }
    // phase 2: irfft, K=256, A=X[b][o][k2], B=Ti[k2][n]
    const float* Xb = X + (size_t)b*128*256;
    for (int k0=0;k0<256;k0+=32){
        __syncthreads();
        #pragma unroll
        for (int p=0;p<16;p++){
            int e = p*256 + tid;
            int o = e >> 5, k = e & 31;
            at[k][o] = Xb[(size_t)o*256 + k0 + k];
        }
        #pragma unroll
        for (int p=0;p<2;p++){
            int k = p*16 + ty;
            *reinterpret_cast<float4*>(&bt[k][tx*4]) =
                *reinterpret_cast<const float4*>(&Ti[(size_t)(k0+k)*4096 + n0 + tx*4]);
        }
        __syncthreads();
        #pragma unroll
        for (int k=0;k<32;k++){
            float4 b4 = *reinterpret_cast<const float4*>(&bt[k][tx*4]);
            float4 a0 = *reinterpret_cast<const float4*>(&at[k][ty*8]);
            float4 a1 = *reinterpret_cast<const float4*>(&at[k][ty*8+4]);
            float av[8]={a0.x,a0.y,a0.z,a0.w,a1.x,a1.y,a1.z,a1.w};
            float bv[4]={b4.x,b4.y,b4.z,b4.w};
            #pragma unroll
            for (int i=0;i<8;i++)
                #pragma unroll
                for (int j=0;j<4;j++) acc[i][j] = fmaf(av[i], bv[j], acc[i][j]);
        }
    }
    // epilogue: bias (+gelu), write back in place
    #pragma unroll
    for (int i=0;i<8;i++){
        int o = ty*8 + i;
        float bias = convB[layer*128 + o];
        float4 v;
        v.x = acc[i][0]+bias; v.y = acc[i][1]+bias;
        v.z = acc[i][2]+bias; v.w = acc[i][3]+bias;
        if (applyGelu){
            v.x = gelu_f(v.x); v.y = gelu_f(v.y);
            v.z = gelu_f(v.z); v.w = gelu_f(v.w);
        }
        *reinterpret_cast<float4*>(&h[((size_t)(b*128+o))*4096 + n0 + tx*4]) = v;
    }
}

// ---------------- head: out[b][n] = fc2 . gelu(fc1 . h[b][:][n] + b1) + b2
__global__ __launch_bounds__(256) void k_head(const float* __restrict__ h,
        const float* __restrict__ fc1W, const float* __restrict__ fc1b,
        const float* __restrict__ fc2W, const float* __restrict__ fc2b,
        float* __restrict__ out){
    int b = blockIdx.y;
    int n = blockIdx.x*256 + threadIdx.x;
    float hreg[128];
    #pragma unroll
    for (int c=0;c<128;c++) hreg[c] = h[((size_t)(b*128+c))*4096 + n];
    float acc = fc2b[0];
    for (int j=0;j<128;j++){
        float s = fc1b[j];
        const float* wrow = fc1W + j*128;
        #pragma unroll
        for (int c=0;c<128;c++) s = fmaf(wrow[c], hreg[c], s);
        acc = fmaf(fc2W[j], gelu_f(s), acc);
    }
    out[((size_t)b<<12) + n] = acc;
}

extern "C" void kernel_launch(void* const* d_in, const int* in_sizes, int n_in,
                              void* d_out, int out_size, void* d_ws, size_t ws_size,
                              hipStream_t stream) {
    const float* x     = (const float*)d_in[0];
    const float* fc0W  = (const float*)d_in[1];
    const float* fc0b  = (const float*)d_in[2];
    const float* gateW = (const float*)d_in[3];
    const float* gateB = (const float*)d_in[4];
    const float* wAre  = (const float*)d_in[5];
    const float* wAim  = (const float*)d_in[6];
    const float* wBre  = (const float*)d_in[7];
    const float* wBim  = (const float*)d_in[8];
    const float* convW = (const float*)d_in[9];
    const float* convB = (const float*)d_in[10];
    const float* fc1W  = (const float*)d_in[11];
    const float* fc1b  = (const float*)d_in[12];
    const float* fc2W  = (const float*)d_in[13];
    const float* fc2b  = (const float*)d_in[14];
    float* out = (float*)d_out;
    float* ws  = (float*)d_ws;

    float* h    = ws + o_h;
    float* Tf   = ws + o_Tf;
    float* Ti   = ws + o_Ti;
    float* Wcre = ws + o_Wcre;
    float* Wcim = ws + o_Wcim;
    float* wl   = ws + o_wl;
    float* wr   = ws + o_wr;
    int*   li   = (int*)(ws + o_li);
    float* wsum = ws + o_wsum;
    float* F    = ws + o_F;
    float* X    = ws + o_X;
    float* Wg   = ws + o_Wg;
    float* magp = ws + o_magp;
    float* gate = ws + o_gate;

    // tables + weight pre-reduction + lift
    k_dft_tables<<<4096, 256, 0, stream>>>(Tf, Ti);
    k_cft_tables<<<160, 128, 0, stream>>>(Wcre, Wcim, wl, wr, li);
    k_wsum<<<dim3(16384,4), 256, 0, stream>>>(wAre, wAim, wBre, wBim, wsum);
    k_h0<<<131072, 256, 0, stream>>>(x, fc0W, fc0b, h);

    for (int layer=0; layer<4; layer++){
        k_cft<<<dim3(64,8), 128, 0, stream>>>(h, Wcre, Wcim, wl, wr, li, magp);
        k_gate<<<64, 128, 0, stream>>>(magp, gateW, gateB, gate, layer);
        k_wg<<<4096, 256, 0, stream>>>(wsum, gate, Wg, layer);
        k_dft<<<dim3(4,128), 256, 0, stream>>>(h, Tf, F);
        k_modemix<<<dim3(64,16), 256, 0, stream>>>(F, Wg, X);
        k_layer<<<dim3(64,64), 256, 0, stream>>>(X, Ti, convW, convB, h,
                                                 layer, layer<3 ? 1:0);
    }
    k_head<<<dim3(16,64), 256, 0, stream>>>(h, fc1W, fc1b, fc2W, fc2b, out);
    (void)in_sizes; (void)n_in; (void)out_size; (void)ws_size;
}

// Round 3
// 2134.716 us; speedup vs baseline: 2.0860x; 2.0860x over previous
//
#include <hip/hip_runtime.h>
#include <math.h>

#define B_SZ 64
#define WID 128
#define NPT 4096
#define MODES 128
#define LSEG 20
#define MCH 8
#define LM 160   // LSEG*MCH

typedef _Float16 half8 __attribute__((ext_vector_type(8)));
typedef float f32x4 __attribute__((ext_vector_type(4)));

#define LO_SCALE 2048.0f
#define LO_INV   (1.0f/2048.0f)

// ---------------- workspace layout (bytes), total ~160.9 MB ----------------
static constexpr size_t BY_F    = 0;                       // fp32 [8192][256]
static constexpr size_t BY_wsum = BY_F + 8388608;          // fp32 [4][4][128][128]
static constexpr size_t BY_Wcre = BY_wsum + 1048576;       // fp32 [160][128]
static constexpr size_t BY_Wcim = BY_Wcre + 81920;
static constexpr size_t BY_wl   = BY_Wcim + 81920;         // fp32 [160] (pad 256)
static constexpr size_t BY_wr   = BY_wl + 1024;
static constexpr size_t BY_li   = BY_wr + 1024;            // int [160]
static constexpr size_t BY_magp = BY_li + 1024;            // fp32 [64][8][128]
static constexpr size_t BY_gate = BY_magp + 262144;        // fp32 [64][128]
static constexpr size_t BY_h    = BY_gate + 32768;         // fp32 [64][128][4096]
static constexpr size_t BY_Tfh  = BY_h + 134217728;        // f16 [256][4096]
static constexpr size_t BY_Tfl  = BY_Tfh + 2097152;
static constexpr size_t BY_Tih  = BY_Tfl + 2097152;        // f16 [4096][256]
static constexpr size_t BY_Til  = BY_Tih + 2097152;
static constexpr size_t BY_Xh   = BY_Til + 2097152;        // f16 [64][128][256]
static constexpr size_t BY_Xl   = BY_Xh + 4194304;
static constexpr size_t BY_end  = BY_Xl + 4194304;         // 160,893,952 B

__device__ __forceinline__ float gelu_f(float x){
    return 0.5f*x*(1.0f+erff(x*0.70710678118654752f));
}
__device__ __forceinline__ void split_f16(float v, _Float16& hi, _Float16& lo){
    hi = (_Float16)v;
    lo = (_Float16)((v - (float)hi)*LO_SCALE);
}

// ---------------- tables (split f16) ----------------
__global__ void k_tables(_Float16* __restrict__ Tfh, _Float16* __restrict__ Tfl,
                         _Float16* __restrict__ Tih, _Float16* __restrict__ Til){
    int idx = blockIdx.x*256 + threadIdx.x;   // 4096*256
    int n = idx >> 8, k2 = idx & 255;
    int f = k2 >> 1;
    int m = (n*f) & 4095;
    double th = (double)m * (3.14159265358979323846/2048.0);
    double s, c; sincos(th, &s, &c);
    float vf = (k2&1) ? (float)(-s) : (float)c;           // fwd: Re=cos, Im=-sin
    _Float16 h1,l1; split_f16(vf, h1, l1);
    Tfh[(size_t)k2*4096 + n] = h1;
    Tfl[(size_t)k2*4096 + n] = l1;
    float vi;                                              // inverse, scale folded into X
    if (k2 == 0)      vi = 1.0f;
    else if (k2 == 1) vi = 0.0f;                           // Im(X[0]) ignored by irfft
    else              vi = vf;
    _Float16 h2,l2; split_f16(vi, h2, l2);
    Tih[(size_t)n*256 + k2] = h2;
    Til[(size_t)n*256 + k2] = l2;
}

__global__ void k_cft_tables(float* __restrict__ Wre, float* __restrict__ Wim,
                             float* __restrict__ wl, float* __restrict__ wr,
                             int* __restrict__ li){
    int idx = blockIdx.x*128 + threadIdx.x;   // 160*128
    if (idx >= LM*MODES) return;
    int lm = idx >> 7;  int f = idx & 127;
    int l = lm / MCH, m = lm % MCH;
    const double PI = 3.14159265358979323846;
    double nodes[8], Tm[8];
    #pragma unroll
    for (int j=0;j<8;j++){
        nodes[j] = -cos((2.0*j+1.0)*PI/16.0);
        Tm[j] = cos((double)m * acos(nodes[j]));
    }
    double wp = (double)f * PI * 0.05;
    double cwre=0.0, cwim=0.0;
    #pragma unroll
    for (int j=0;j<8;j++){
        double sj, cj; sincos(nodes[j]*wp, &sj, &cj);
        cwre += Tm[j]*cj;
        cwim -= Tm[j]*sj;
    }
    cwre *= 0.025; cwim *= 0.025;
    int r = (f*l) % 20;
    double sa = 2.0*PI*(double)r/20.0;
    double shre = cos(sa), shim = -sin(sa);
    Wre[lm*128+f] = (float)(shre*cwre - shim*cwim);
    Wim[lm*128+f] = (float)(shre*cwim + shim*cwre);
    if (f == 0){
        double v = (double)l/20.0 + 0.025*(nodes[m]+1.0);
        int rr = (int)ceil(v*4095.0);
        if (rr > 4095) rr = 4095;
        if (rr < 1) rr = 1;
        int le = rr-1;
        double tl = (double)le/4095.0, tr = (double)rr/4095.0;
        double wrv = (v - tl)/(tr - tl);
        li[lm] = le;
        wl[lm] = (float)(1.0 - wrv);
        wr[lm] = (float)wrv;
    }
}

// sum wA/wB over mode axis
__global__ void k_wsum(const float* __restrict__ wAre, const float* __restrict__ wAim,
                       const float* __restrict__ wBre, const float* __restrict__ wBim,
                       float* __restrict__ out){
    int row  = blockIdx.x*4 + (threadIdx.x>>6);    // 65536 rows per tensor
    int lane = threadIdx.x & 63;
    const float* src = (blockIdx.y==0)?wAre:(blockIdx.y==1)?wAim:(blockIdx.y==2)?wBre:wBim;
    float v = src[(size_t)row*128 + lane] + src[(size_t)row*128 + 64 + lane];
    #pragma unroll
    for (int o=32;o>0;o>>=1) v += __shfl_down(v, o);
    if (lane==0) out[(size_t)blockIdx.y*65536 + row] = v;
}

// ---------------- lift ----------------
__global__ void k_h0(const float* __restrict__ x, const float* __restrict__ w0,
                     const float* __restrict__ b0, float* __restrict__ h){
    size_t idx = (size_t)blockIdx.x*256 + threadIdx.x;
    int n = idx & 4095;
    int w = (idx >> 12) & 127;
    int b = idx >> 19;
    float g = (float)n * (1.0f/4095.0f);
    h[idx] = x[((size_t)b<<12) + n]*w0[w*2] + g*w0[w*2+1] + b0[w];
}

// ---------------- CFT magnitude ----------------
__global__ void k_cft(const float* __restrict__ h, const float* __restrict__ Wre,
                      const float* __restrict__ Wim, const float* __restrict__ wl,
                      const float* __restrict__ wr, const int* __restrict__ li,
                      float* __restrict__ magp){
    int b = blockIdx.x, cg = blockIdx.y;
    int f = threadIdx.x;   // 128
    __shared__ float sig[LM];
    __shared__ float swl[LM], swr[LM];
    __shared__ int   sli[LM];
    for (int s=f; s<LM; s+=128){ swl[s]=wl[s]; swr[s]=wr[s]; sli[s]=li[s]; }
    __syncthreads();
    float acc = 0.f;
    for (int cc=0; cc<16; cc++){
        int c = cg*16 + cc;
        const float* hr = h + ((size_t)(b*128+c))*4096;
        for (int s=f; s<LM; s+=128){
            int le = sli[s];
            sig[s] = swl[s]*hr[le] + swr[s]*hr[le+1];
        }
        __syncthreads();
        float re=0.f, im=0.f;
        #pragma unroll 8
        for (int s=0;s<LM;s++){
            float sv = sig[s];
            re = fmaf(sv, Wre[s*128+f], re);
            im = fmaf(sv, Wim[s*128+f], im);
        }
        acc += sqrtf(re*re+im*im);
        __syncthreads();
    }
    magp[(b*8+cg)*128 + f] = acc;
}

__global__ void k_gate(const float* __restrict__ magp, const float* __restrict__ gW,
                       const float* __restrict__ gB, float* __restrict__ gate, int layer){
    int b = blockIdx.x, w = threadIdx.x;
    __shared__ float ms[128];
    float s = 0.f;
    #pragma unroll
    for (int g=0; g<8; g++) s += magp[(b*8+g)*128 + w];
    ms[w] = s * (1.0f/128.0f);
    __syncthreads();
    const float* gwr = gW + ((size_t)layer*128 + w)*128;
    float a = gB[layer*128 + w];
    #pragma unroll 8
    for (int fq=0; fq<128; fq++) a = fmaf(ms[fq], gwr[fq], a);
    gate[b*128+w] = 1.0f/(1.0f+expf(-a));
}

// ---------------- forward DFT (MFMA, fp16 split): F = h[8192][4096] x Tf^T ----------------
// grid: 512 flat blocks, XCD-swizzled so same-row blocks share an XCD L2.
__global__ __launch_bounds__(256) void k_fdft(const float* __restrict__ h,
        const _Float16* __restrict__ Tfh, const _Float16* __restrict__ Tfl,
        float* __restrict__ F){
    __shared__ _Float16 Ah[64][40], Al[64][40], Bh[64][40], Bl[64][40];
    int id = blockIdx.x;
    int swz = (id & 7)*64 + (id >> 3);        // bijective for 512
    int bx = swz & 3, by = swz >> 2;
    int col0 = bx*64, row0 = by*64;
    int tid = threadIdx.x;
    int lane = tid & 63, w = tid >> 6;
    int wr = (w>>1)*32, wc = (w&1)*32;
    int l15 = lane & 15, l4 = lane >> 4;
    f32x4 acc[2][2] = {}; f32x4 acc2[2][2] = {};
    int srow = tid >> 2, sseg = tid & 3;
    const size_t arow = (size_t)(row0 + srow)*4096;
    const size_t brow = (size_t)(col0 + srow)*4096;
    for (int k0 = 0; k0 < 4096; k0 += 32){
        float4 a0 = *reinterpret_cast<const float4*>(&h[arow + k0 + sseg*8]);
        float4 a1 = *reinterpret_cast<const float4*>(&h[arow + k0 + sseg*8 + 4]);
        float av[8] = {a0.x,a0.y,a0.z,a0.w,a1.x,a1.y,a1.z,a1.w};
        half8 vh, vl;
        #pragma unroll
        for (int j=0;j<8;j++){ _Float16 hi,lo; split_f16(av[j],hi,lo); vh[j]=hi; vl[j]=lo; }
        *reinterpret_cast<half8*>(&Ah[srow][sseg*8]) = vh;
        *reinterpret_cast<half8*>(&Al[srow][sseg*8]) = vl;
        *reinterpret_cast<half8*>(&Bh[srow][sseg*8]) =
            *reinterpret_cast<const half8*>(&Tfh[brow + k0 + sseg*8]);
        *reinterpret_cast<half8*>(&Bl[srow][sseg*8]) =
            *reinterpret_cast<const half8*>(&Tfl[brow + k0 + sseg*8]);
        __syncthreads();
        half8 fah[2], fal[2], fbh[2], fbl[2];
        #pragma unroll
        for (int i=0;i<2;i++){
            fah[i] = *reinterpret_cast<const half8*>(&Ah[wr + i*16 + l15][l4*8]);
            fal[i] = *reinterpret_cast<const half8*>(&Al[wr + i*16 + l15][l4*8]);
            fbh[i] = *reinterpret_cast<const half8*>(&Bh[wc + i*16 + l15][l4*8]);
            fbl[i] = *reinterpret_cast<const half8*>(&Bl[wc + i*16 + l15][l4*8]);
        }
        #pragma unroll
        for (int i=0;i<2;i++)
            #pragma unroll
            for (int j=0;j<2;j++){
                acc[i][j]  = __builtin_amdgcn_mfma_f32_16x16x32_f16(fah[i], fbh[j], acc[i][j], 0,0,0);
                acc2[i][j] = __builtin_amdgcn_mfma_f32_16x16x32_f16(fah[i], fbl[j], acc2[i][j],0,0,0);
                acc2[i][j] = __builtin_amdgcn_mfma_f32_16x16x32_f16(fal[i], fbh[j], acc2[i][j],0,0,0);
            }
        __syncthreads();
    }
    #pragma unroll
    for (int i=0;i<2;i++)
        #pragma unroll
        for (int j=0;j<2;j++)
            #pragma unroll
            for (int r=0;r<4;r++){
                int row = row0 + wr + i*16 + l4*4 + r;
                int col = col0 + wc + j*16 + l15;
                F[(size_t)row*256 + col] = acc[i][j][r] + acc2[i][j][r]*LO_INV;
            }
}

// ---------------- mode mix without Wg: X = g*(F.wA) + (1-g)*(F.wB), scaled, split ----------------
__global__ __launch_bounds__(256) void k_modemix(const float* __restrict__ F,
        const float* __restrict__ wsum, const float* __restrict__ gate,
        _Float16* __restrict__ Xh, _Float16* __restrict__ Xl, int layer){
    int b = blockIdx.x, og = blockIdx.y;       // 16 groups of 8 o
    __shared__ float Fs[16][256];
    __shared__ float Wa_re[128][8], Wa_im[128][8], Wb_re[128][8], Wb_im[128][8];
    int tid = threadIdx.x;
    for (int e=tid; e<1024; e+=256){
        int i = e>>3, oo = e&7;
        size_t base = ((size_t)layer*128 + i)*128 + og*8 + oo;
        Wa_re[i][oo] = wsum[0*65536 + base];
        Wa_im[i][oo] = wsum[1*65536 + base];
        Wb_re[i][oo] = wsum[2*65536 + base];
        Wb_im[i][oo] = wsum[3*65536 + base];
    }
    int f = tid & 127, half = tid >> 7;
    float pre[4]={},pim[4]={},qre[4]={},qim[4]={};
    for (int i0=0;i0<128;i0+=16){
        for (int e=tid; e<4096; e+=256){
            int ii = e >> 8, k2 = e & 255;
            Fs[ii][k2] = F[((size_t)(b*128 + i0+ii))*256 + k2];
        }
        __syncthreads();
        #pragma unroll
        for (int ii=0; ii<16; ii++){
            float fre = Fs[ii][2*f], fim = Fs[ii][2*f+1];
            int i = i0+ii;
            #pragma unroll
            for (int q=0;q<4;q++){
                int oo = half*4+q;
                float are=Wa_re[i][oo], aim=Wa_im[i][oo];
                float bre=Wb_re[i][oo], bim=Wb_im[i][oo];
                pre[q] = fmaf(fre, are, fmaf(-fim, aim, pre[q]));
                pim[q] = fmaf(fre, aim, fmaf( fim, are, pim[q]));
                qre[q] = fmaf(fre, bre, fmaf(-fim, bim, qre[q]));
                qim[q] = fmaf(fre, bim, fmaf( fim, bre, qim[q]));
            }
        }
        __syncthreads();
    }
    #pragma unroll
    for (int q=0;q<4;q++){
        int o = og*8 + half*4 + q;
        float g = gate[b*128+o];
        float xre = g*pre[q] + (1.f-g)*qre[q];
        float xim = g*pim[q] + (1.f-g)*qim[q];
        float s = (f==0) ? (1.0f/4096.0f) : (2.0f/4096.0f);
        xre *= s; xim *= s;
        if (f==0) xim = 0.f;
        size_t base = ((size_t)(b*128+o))*256 + 2*f;
        _Float16 h1,l1; split_f16(xre,h1,l1); Xh[base]=h1;   Xl[base]=l1;
        _Float16 h2,l2; split_f16(xim,h2,l2); Xh[base+1]=h2; Xl[base+1]=l2;
    }
}

// ---------------- fused in-place irfft + conv + bias + gelu (MFMA, fp16 split) ----------------
__global__ __launch_bounds__(256) void k_flayer(
    const _Float16* __restrict__ Xh, const _Float16* __restrict__ Xl,
    const _Float16* __restrict__ Tih, const _Float16* __restrict__ Til,
    const float* __restrict__ convW, const float* __restrict__ convB,
    float* __restrict__ h, int layer, int applyGelu){
    __shared__ char smem[55296];
    _Float16 (*Bch)[136] = (_Float16(*)[136])(smem);            // 17,408 B
    _Float16 (*Bcl)[136] = (_Float16(*)[136])(smem + 17408);    // 17,408 B
    _Float16 (*Bsh)[40]  = (_Float16(*)[40])(smem);             // phase-2 reuse
    _Float16 (*Bsl)[40]  = (_Float16(*)[40])(smem + 5120);
    _Float16 (*Ash)[40]  = (_Float16(*)[40])(smem + 34816);
    _Float16 (*Asl)[40]  = (_Float16(*)[40])(smem + 45056);
    int n0 = blockIdx.x*64;
    int b  = blockIdx.y;
    int tid = threadIdx.x;
    int lane = tid & 63, w = tid >> 6;
    int l15 = lane & 15, l4 = lane >> 4;
    int wr = w*32;
    f32x4 acc[2][4] = {}; f32x4 acc2[2][4] = {};
    // stage transposed h tile: Bch[n][c] (reads complete before any global write)
    {
        int cpair = tid >> 3;          // 0..31
        int seg   = tid & 7;           // n-segment of 8
        #pragma unroll
        for (int p=0;p<2;p++){
            int c = p*64 + cpair*2;
            const float* r0 = &h[((size_t)(b*128+c))*4096 + n0 + seg*8];
            const float* r1 = r0 + 4096;
            float4 x00 = *reinterpret_cast<const float4*>(r0);
            float4 x01 = *reinterpret_cast<const float4*>(r0+4);
            float4 x10 = *reinterpret_cast<const float4*>(r1);
            float4 x11 = *reinterpret_cast<const float4*>(r1+4);
            float v0[8]={x00.x,x00.y,x00.z,x00.w,x01.x,x01.y,x01.z,x01.w};
            float v1[8]={x10.x,x10.y,x10.z,x10.w,x11.x,x11.y,x11.z,x11.w};
            #pragma unroll
            for (int j=0;j<8;j++){
                int n = seg*8+j;
                _Float16 h0,l0,h1,l1;
                split_f16(v0[j],h0,l0);
                split_f16(v1[j],h1,l1);
                Bch[n][c] = h0; Bch[n][c+1] = h1;
                Bcl[n][c] = l0; Bcl[n][c+1] = l1;
            }
        }
    }
    __syncthreads();
    int so2 = tid >> 2, sseg = tid & 3;
    // phase 1: pointwise conv, K=128, A=convW split, B=Bch
    const float* cw = convW + (size_t)layer*16384;
    for (int k0=0;k0<128;k0+=32){
        #pragma unroll
        for (int p=0;p<2;p++){
            int o = p*64 + so2;
            const float* wp = &cw[(size_t)o*128 + k0 + sseg*8];
            float4 w0 = *reinterpret_cast<const float4*>(wp);
            float4 w1 = *reinterpret_cast<const float4*>(wp+4);
            float wv[8]={w0.x,w0.y,w0.z,w0.w,w1.x,w1.y,w1.z,w1.w};
            half8 vh,vl;
            #pragma unroll
            for (int j=0;j<8;j++){ _Float16 hi,lo; split_f16(wv[j],hi,lo); vh[j]=hi; vl[j]=lo; }
            *reinterpret_cast<half8*>(&Ash[o][sseg*8]) = vh;
            *reinterpret_cast<half8*>(&Asl[o][sseg*8]) = vl;
        }
        __syncthreads();
        half8 ah[2],al[2],bh[4],bl[4];
        #pragma unroll
        for (int i=0;i<2;i++){
            ah[i] = *reinterpret_cast<const half8*>(&Ash[wr+i*16+l15][l4*8]);
            al[i] = *reinterpret_cast<const half8*>(&Asl[wr+i*16+l15][l4*8]);
        }
        #pragma unroll
        for (int j=0;j<4;j++){
            bh[j] = *reinterpret_cast<const half8*>(&Bch[j*16+l15][k0+l4*8]);
            bl[j] = *reinterpret_cast<const half8*>(&Bcl[j*16+l15][k0+l4*8]);
        }
        #pragma unroll
        for (int i=0;i<2;i++)
            #pragma unroll
            for (int j=0;j<4;j++){
                acc[i][j]  = __builtin_amdgcn_mfma_f32_16x16x32_f16(ah[i], bh[j], acc[i][j], 0,0,0);
                acc2[i][j] = __builtin_amdgcn_mfma_f32_16x16x32_f16(ah[i], bl[j], acc2[i][j],0,0,0);
                acc2[i][j] = __builtin_amdgcn_mfma_f32_16x16x32_f16(al[i], bh[j], acc2[i][j],0,0,0);
            }
        __syncthreads();
    }
    // phase 2: irfft, K=256, A=X split, B=Tit split
    for (int k0=0;k0<256;k0+=32){
        #pragma unroll
        for (int p=0;p<2;p++){
            int o = p*64 + so2;
            size_t xi = ((size_t)(b*128+o))*256 + k0 + sseg*8;
            *reinterpret_cast<half8*>(&Ash[o][sseg*8]) = *reinterpret_cast<const half8*>(&Xh[xi]);
            *reinterpret_cast<half8*>(&Asl[o][sseg*8]) = *reinterpret_cast<const half8*>(&Xl[xi]);
        }
        {
            size_t ti = ((size_t)(n0+so2))*256 + k0 + sseg*8;
            *reinterpret_cast<half8*>(&Bsh[so2][sseg*8]) = *reinterpret_cast<const half8*>(&Tih[ti]);
            *reinterpret_cast<half8*>(&Bsl[so2][sseg*8]) = *reinterpret_cast<const half8*>(&Til[ti]);
        }
        __syncthreads();
        half8 ah[2],al[2],bh[4],bl[4];
        #pragma unroll
        for (int i=0;i<2;i++){
            ah[i] = *reinterpret_cast<const half8*>(&Ash[wr+i*16+l15][l4*8]);
            al[i] = *reinterpret_cast<const half8*>(&Asl[wr+i*16+l15][l4*8]);
        }
        #pragma unroll
        for (int j=0;j<4;j++){
            bh[j] = *reinterpret_cast<const half8*>(&Bsh[j*16+l15][l4*8]);
            bl[j] = *reinterpret_cast<const half8*>(&Bsl[j*16+l15][l4*8]);
        }
        #pragma unroll
        for (int i=0;i<2;i++)
            #pragma unroll
            for (int j=0;j<4;j++){
                acc[i][j]  = __builtin_amdgcn_mfma_f32_16x16x32_f16(ah[i], bh[j], acc[i][j], 0,0,0);
                acc2[i][j] = __builtin_amdgcn_mfma_f32_16x16x32_f16(ah[i], bl[j], acc2[i][j],0,0,0);
                acc2[i][j] = __builtin_amdgcn_mfma_f32_16x16x32_f16(al[i], bh[j], acc2[i][j],0,0,0);
            }
        __syncthreads();
    }
    // epilogue
    #pragma unroll
    for (int i=0;i<2;i++)
        #pragma unroll
        for (int j=0;j<4;j++)
            #pragma unroll
            for (int r=0;r<4;r++){
                int o = wr + i*16 + l4*4 + r;
                int n = n0 + j*16 + l15;
                float v = acc[i][j][r] + acc2[i][j][r]*LO_INV + convB[layer*128+o];
                if (applyGelu) v = gelu_f(v);
                h[((size_t)(b*128+o))*4096 + n] = v;
            }
}

// ---------------- head ----------------
__global__ __launch_bounds__(256) void k_head(const float* __restrict__ h,
        const float* __restrict__ fc1W, const float* __restrict__ fc1b,
        const float* __restrict__ fc2W, const float* __restrict__ fc2b,
        float* __restrict__ out){
    int b = blockIdx.y;
    int n = blockIdx.x*256 + threadIdx.x;
    float hreg[128];
    #pragma unroll
    for (int c=0;c<128;c++) hreg[c] = h[((size_t)(b*128+c))*4096 + n];
    float acc = fc2b[0];
    for (int j=0;j<128;j++){
        float s = fc1b[j];
        const float* wrow = fc1W + j*128;
        #pragma unroll
        for (int c=0;c<128;c++) s = fmaf(wrow[c], hreg[c], s);
        acc = fmaf(fc2W[j], gelu_f(s), acc);
    }
    out[((size_t)b<<12) + n] = acc;
}

extern "C" void kernel_launch(void* const* d_in, const int* in_sizes, int n_in,
                              void* d_out, int out_size, void* d_ws, size_t ws_size,
                              hipStream_t stream) {
    const float* x     = (const float*)d_in[0];
    const float* fc0W  = (const float*)d_in[1];
    const float* fc0b  = (const float*)d_in[2];
    const float* gateW = (const float*)d_in[3];
    const float* gateB = (const float*)d_in[4];
    const float* wAre  = (const float*)d_in[5];
    const float* wAim  = (const float*)d_in[6];
    const float* wBre  = (const float*)d_in[7];
    const float* wBim  = (const float*)d_in[8];
    const float* convW = (const float*)d_in[9];
    const float* convB = (const float*)d_in[10];
    const float* fc1W  = (const float*)d_in[11];
    const float* fc1b  = (const float*)d_in[12];
    const float* fc2W  = (const float*)d_in[13];
    const float* fc2b  = (const float*)d_in[14];
    float* out = (float*)d_out;
    char*  wsb = (char*)d_ws;

    float* F    = (float*)(wsb + BY_F);
    float* wsum = (float*)(wsb + BY_wsum);
    float* Wcre = (float*)(wsb + BY_Wcre);
    float* Wcim = (float*)(wsb + BY_Wcim);
    float* wl   = (float*)(wsb + BY_wl);
    float* wr   = (float*)(wsb + BY_wr);
    int*   li   = (int*)(wsb + BY_li);
    float* magp = (float*)(wsb + BY_magp);
    float* gate = (float*)(wsb + BY_gate);
    float* h    = (float*)(wsb + BY_h);
    _Float16* Tfh = (_Float16*)(wsb + BY_Tfh);
    _Float16* Tfl = (_Float16*)(wsb + BY_Tfl);
    _Float16* Tih = (_Float16*)(wsb + BY_Tih);
    _Float16* Til = (_Float16*)(wsb + BY_Til);
    _Float16* Xh  = (_Float16*)(wsb + BY_Xh);
    _Float16* Xl  = (_Float16*)(wsb + BY_Xl);

    k_tables<<<4096, 256, 0, stream>>>(Tfh, Tfl, Tih, Til);
    k_cft_tables<<<160, 128, 0, stream>>>(Wcre, Wcim, wl, wr, li);
    k_wsum<<<dim3(16384,4), 256, 0, stream>>>(wAre, wAim, wBre, wBim, wsum);
    k_h0<<<131072, 256, 0, stream>>>(x, fc0W, fc0b, h);

    for (int layer=0; layer<4; layer++){
        k_cft<<<dim3(64,8), 128, 0, stream>>>(h, Wcre, Wcim, wl, wr, li, magp);
        k_gate<<<64, 128, 0, stream>>>(magp, gateW, gateB, gate, layer);
        k_fdft<<<512, 256, 0, stream>>>(h, Tfh, Tfl, F);
        k_modemix<<<dim3(64,16), 256, 0, stream>>>(F, wsum, gate, Xh, Xl, layer);
        k_flayer<<<dim3(64,64), 256, 0, stream>>>(Xh, Xl, Tih, Til, convW, convB,
                                                  h, layer, layer<3 ? 1:0);
    }
    k_head<<<dim3(16,64), 256, 0, stream>>>(h, fc1W, fc1b, fc2W, fc2b, out);
    (void)in_sizes; (void)n_in; (void)out_size; (void)ws_size;
}

// Round 4
// 1695.339 us; speedup vs baseline: 2.6266x; 1.2592x over previous
//
#include <hip/hip_runtime.h>
#include <math.h>

#define B_SZ 64
#define WID 128
#define NPT 4096
#define MODES 128
#define LSEG 20
#define MCH 8
#define LM 160   // LSEG*MCH

typedef _Float16 half8 __attribute__((ext_vector_type(8)));
typedef float f32x4 __attribute__((ext_vector_type(4)));

#define LO_SCALE 2048.0f
#define LO_INV   (1.0f/2048.0f)

// ---------------- workspace layout (bytes), total ~160.9 MB ----------------
static constexpr size_t BY_F    = 0;                       // fp32 [8192][256]
static constexpr size_t BY_wsum = BY_F + 8388608;          // fp32 [4][4][128][128]
static constexpr size_t BY_Wcre = BY_wsum + 1048576;       // fp32 [160][128]
static constexpr size_t BY_Wcim = BY_Wcre + 81920;
static constexpr size_t BY_wl   = BY_Wcim + 81920;         // fp32 [160] (pad 256)
static constexpr size_t BY_wr   = BY_wl + 1024;
static constexpr size_t BY_li   = BY_wr + 1024;            // int [160]
static constexpr size_t BY_magp = BY_li + 1024;            // fp32 [64][8][128]
static constexpr size_t BY_gate = BY_magp + 262144;        // fp32 [64][128]
static constexpr size_t BY_h    = BY_gate + 32768;         // fp32 [64][128][4096]
static constexpr size_t BY_Tfh  = BY_h + 134217728;        // f16 [256][4096]
static constexpr size_t BY_Tfl  = BY_Tfh + 2097152;
static constexpr size_t BY_Tih  = BY_Tfl + 2097152;        // f16 [4096][256]
static constexpr size_t BY_Til  = BY_Tih + 2097152;
static constexpr size_t BY_Xh   = BY_Til + 2097152;        // f16 [64][128][256]
static constexpr size_t BY_Xl   = BY_Xh + 4194304;
static constexpr size_t BY_end  = BY_Xl + 4194304;         // 160,893,952 B

__device__ __forceinline__ float gelu_f(float x){
    return 0.5f*x*(1.0f+erff(x*0.70710678118654752f));
}
__device__ __forceinline__ void split_f16(float v, _Float16& hi, _Float16& lo){
    hi = (_Float16)v;
    lo = (_Float16)((v - (float)hi)*LO_SCALE);
}

// ---------------- tables (split f16) ----------------
__global__ void k_tables(_Float16* __restrict__ Tfh, _Float16* __restrict__ Tfl,
                         _Float16* __restrict__ Tih, _Float16* __restrict__ Til){
    int idx = blockIdx.x*256 + threadIdx.x;   // 4096*256
    int n = idx >> 8, k2 = idx & 255;
    int f = k2 >> 1;
    int m = (n*f) & 4095;
    double th = (double)m * (3.14159265358979323846/2048.0);
    double s, c; sincos(th, &s, &c);
    float vf = (k2&1) ? (float)(-s) : (float)c;           // fwd: Re=cos, Im=-sin
    _Float16 h1,l1; split_f16(vf, h1, l1);
    Tfh[(size_t)k2*4096 + n] = h1;
    Tfl[(size_t)k2*4096 + n] = l1;
    float vi;                                              // inverse, scale folded into X
    if (k2 == 0)      vi = 1.0f;
    else if (k2 == 1) vi = 0.0f;                           // Im(X[0]) ignored by irfft
    else              vi = vf;
    _Float16 h2,l2; split_f16(vi, h2, l2);
    Tih[(size_t)n*256 + k2] = h2;
    Til[(size_t)n*256 + k2] = l2;
}

__global__ void k_cft_tables(float* __restrict__ Wre, float* __restrict__ Wim,
                             float* __restrict__ wl, float* __restrict__ wr,
                             int* __restrict__ li){
    int idx = blockIdx.x*128 + threadIdx.x;   // 160*128
    if (idx >= LM*MODES) return;
    int lm = idx >> 7;  int f = idx & 127;
    int l = lm / MCH, m = lm % MCH;
    const double PI = 3.14159265358979323846;
    double nodes[8], Tm[8];
    #pragma unroll
    for (int j=0;j<8;j++){
        nodes[j] = -cos((2.0*j+1.0)*PI/16.0);
        Tm[j] = cos((double)m * acos(nodes[j]));
    }
    double wp = (double)f * PI * 0.05;
    double cwre=0.0, cwim=0.0;
    #pragma unroll
    for (int j=0;j<8;j++){
        double sj, cj; sincos(nodes[j]*wp, &sj, &cj);
        cwre += Tm[j]*cj;
        cwim -= Tm[j]*sj;
    }
    cwre *= 0.025; cwim *= 0.025;
    int r = (f*l) % 20;
    double sa = 2.0*PI*(double)r/20.0;
    double shre = cos(sa), shim = -sin(sa);
    Wre[lm*128+f] = (float)(shre*cwre - shim*cwim);
    Wim[lm*128+f] = (float)(shre*cwim + shim*cwre);
    if (f == 0){
        double v = (double)l/20.0 + 0.025*(nodes[m]+1.0);
        int rr = (int)ceil(v*4095.0);
        if (rr > 4095) rr = 4095;
        if (rr < 1) rr = 1;
        int le = rr-1;
        double tl = (double)le/4095.0, tr = (double)rr/4095.0;
        double wrv = (v - tl)/(tr - tl);
        li[lm] = le;
        wl[lm] = (float)(1.0 - wrv);
        wr[lm] = (float)wrv;
    }
}

// sum wA/wB over mode axis
__global__ void k_wsum(const float* __restrict__ wAre, const float* __restrict__ wAim,
                       const float* __restrict__ wBre, const float* __restrict__ wBim,
                       float* __restrict__ out){
    int row  = blockIdx.x*4 + (threadIdx.x>>6);    // 65536 rows per tensor
    int lane = threadIdx.x & 63;
    const float* src = (blockIdx.y==0)?wAre:(blockIdx.y==1)?wAim:(blockIdx.y==2)?wBre:wBim;
    float v = src[(size_t)row*128 + lane] + src[(size_t)row*128 + 64 + lane];
    #pragma unroll
    for (int o=32;o>0;o>>=1) v += __shfl_down(v, o);
    if (lane==0) out[(size_t)blockIdx.y*65536 + row] = v;
}

// ---------------- lift ----------------
__global__ void k_h0(const float* __restrict__ x, const float* __restrict__ w0,
                     const float* __restrict__ b0, float* __restrict__ h){
    size_t idx = (size_t)blockIdx.x*256 + threadIdx.x;
    int n = idx & 4095;
    int w = (idx >> 12) & 127;
    int b = idx >> 19;
    float g = (float)n * (1.0f/4095.0f);
    h[idx] = x[((size_t)b<<12) + n]*w0[w*2] + g*w0[w*2+1] + b0[w];
}

// ---------------- CFT magnitude ----------------
__global__ void k_cft(const float* __restrict__ h, const float* __restrict__ Wre,
                      const float* __restrict__ Wim, const float* __restrict__ wl,
                      const float* __restrict__ wr, const int* __restrict__ li,
                      float* __restrict__ magp){
    int b = blockIdx.x, cg = blockIdx.y;
    int f = threadIdx.x;   // 128
    __shared__ float sig[LM];
    __shared__ float swl[LM], swr[LM];
    __shared__ int   sli[LM];
    for (int s=f; s<LM; s+=128){ swl[s]=wl[s]; swr[s]=wr[s]; sli[s]=li[s]; }
    __syncthreads();
    float acc = 0.f;
    for (int cc=0; cc<16; cc++){
        int c = cg*16 + cc;
        const float* hr = h + ((size_t)(b*128+c))*4096;
        for (int s=f; s<LM; s+=128){
            int le = sli[s];
            sig[s] = swl[s]*hr[le] + swr[s]*hr[le+1];
        }
        __syncthreads();
        float re=0.f, im=0.f;
        #pragma unroll 8
        for (int s=0;s<LM;s++){
            float sv = sig[s];
            re = fmaf(sv, Wre[s*128+f], re);
            im = fmaf(sv, Wim[s*128+f], im);
        }
        acc += sqrtf(re*re+im*im);
        __syncthreads();
    }
    magp[(b*8+cg)*128 + f] = acc;
}

__global__ void k_gate(const float* __restrict__ magp, const float* __restrict__ gW,
                       const float* __restrict__ gB, float* __restrict__ gate, int layer){
    int b = blockIdx.x, w = threadIdx.x;
    __shared__ float ms[128];
    float s = 0.f;
    #pragma unroll
    for (int g=0; g<8; g++) s += magp[(b*8+g)*128 + w];
    ms[w] = s * (1.0f/128.0f);
    __syncthreads();
    const float* gwr = gW + ((size_t)layer*128 + w)*128;
    float a = gB[layer*128 + w];
    #pragma unroll 8
    for (int fq=0; fq<128; fq++) a = fmaf(ms[fq], gwr[fq], a);
    gate[b*128+w] = 1.0f/(1.0f+expf(-a));
}

// ---------------- forward DFT (MFMA, fp16 split): F = h[8192][4096] x Tf^T ----------------
__global__ __launch_bounds__(256) void k_fdft(const float* __restrict__ h,
        const _Float16* __restrict__ Tfh, const _Float16* __restrict__ Tfl,
        float* __restrict__ F){
    __shared__ _Float16 Ah[64][40], Al[64][40], Bh[64][40], Bl[64][40];
    int id = blockIdx.x;
    int swz = (id & 7)*64 + (id >> 3);        // bijective for 512
    int bx = swz & 3, by = swz >> 2;
    int col0 = bx*64, row0 = by*64;
    int tid = threadIdx.x;
    int lane = tid & 63, w = tid >> 6;
    int wr = (w>>1)*32, wc = (w&1)*32;
    int l15 = lane & 15, l4 = lane >> 4;
    f32x4 acc[2][2] = {}; f32x4 acc2[2][2] = {};
    int srow = tid >> 2, sseg = tid & 3;
    const size_t arow = (size_t)(row0 + srow)*4096;
    const size_t brow = (size_t)(col0 + srow)*4096;
    for (int k0 = 0; k0 < 4096; k0 += 32){
        float4 a0 = *reinterpret_cast<const float4*>(&h[arow + k0 + sseg*8]);
        float4 a1 = *reinterpret_cast<const float4*>(&h[arow + k0 + sseg*8 + 4]);
        float av[8] = {a0.x,a0.y,a0.z,a0.w,a1.x,a1.y,a1.z,a1.w};
        half8 vh, vl;
        #pragma unroll
        for (int j=0;j<8;j++){ _Float16 hi,lo; split_f16(av[j],hi,lo); vh[j]=hi; vl[j]=lo; }
        *reinterpret_cast<half8*>(&Ah[srow][sseg*8]) = vh;
        *reinterpret_cast<half8*>(&Al[srow][sseg*8]) = vl;
        *reinterpret_cast<half8*>(&Bh[srow][sseg*8]) =
            *reinterpret_cast<const half8*>(&Tfh[brow + k0 + sseg*8]);
        *reinterpret_cast<half8*>(&Bl[srow][sseg*8]) =
            *reinterpret_cast<const half8*>(&Tfl[brow + k0 + sseg*8]);
        __syncthreads();
        half8 fah[2], fal[2], fbh[2], fbl[2];
        #pragma unroll
        for (int i=0;i<2;i++){
            fah[i] = *reinterpret_cast<const half8*>(&Ah[wr + i*16 + l15][l4*8]);
            fal[i] = *reinterpret_cast<const half8*>(&Al[wr + i*16 + l15][l4*8]);
            fbh[i] = *reinterpret_cast<const half8*>(&Bh[wc + i*16 + l15][l4*8]);
            fbl[i] = *reinterpret_cast<const half8*>(&Bl[wc + i*16 + l15][l4*8]);
        }
        #pragma unroll
        for (int i=0;i<2;i++)
            #pragma unroll
            for (int j=0;j<2;j++){
                acc[i][j]  = __builtin_amdgcn_mfma_f32_16x16x32_f16(fah[i], fbh[j], acc[i][j], 0,0,0);
                acc2[i][j] = __builtin_amdgcn_mfma_f32_16x16x32_f16(fah[i], fbl[j], acc2[i][j],0,0,0);
                acc2[i][j] = __builtin_amdgcn_mfma_f32_16x16x32_f16(fal[i], fbh[j], acc2[i][j],0,0,0);
            }
        __syncthreads();
    }
    #pragma unroll
    for (int i=0;i<2;i++)
        #pragma unroll
        for (int j=0;j<2;j++)
            #pragma unroll
            for (int r=0;r<4;r++){
                int row = row0 + wr + i*16 + l4*4 + r;
                int col = col0 + wc + j*16 + l15;
                F[(size_t)row*256 + col] = acc[i][j][r] + acc2[i][j][r]*LO_INV;
            }
}

// ---------------- mode mix: X = g*(F.wA) + (1-g)*(F.wB), scaled, split ----------------
__global__ __launch_bounds__(256) void k_modemix(const float* __restrict__ F,
        const float* __restrict__ wsum, const float* __restrict__ gate,
        _Float16* __restrict__ Xh, _Float16* __restrict__ Xl, int layer){
    int b = blockIdx.x, og = blockIdx.y;       // 16 groups of 8 o
    __shared__ float Fs[16][256];
    __shared__ float Wa_re[128][8], Wa_im[128][8], Wb_re[128][8], Wb_im[128][8];
    int tid = threadIdx.x;
    for (int e=tid; e<1024; e+=256){
        int i = e>>3, oo = e&7;
        size_t base = ((size_t)layer*128 + i)*128 + og*8 + oo;
        Wa_re[i][oo] = wsum[0*65536 + base];
        Wa_im[i][oo] = wsum[1*65536 + base];
        Wb_re[i][oo] = wsum[2*65536 + base];
        Wb_im[i][oo] = wsum[3*65536 + base];
    }
    int f = tid & 127, half = tid >> 7;
    float pre[4]={},pim[4]={},qre[4]={},qim[4]={};
    for (int i0=0;i0<128;i0+=16){
        for (int e=tid; e<4096; e+=256){
            int ii = e >> 8, k2 = e & 255;
            Fs[ii][k2] = F[((size_t)(b*128 + i0+ii))*256 + k2];
        }
        __syncthreads();
        #pragma unroll
        for (int ii=0; ii<16; ii++){
            float fre = Fs[ii][2*f], fim = Fs[ii][2*f+1];
            int i = i0+ii;
            #pragma unroll
            for (int q=0;q<4;q++){
                int oo = half*4+q;
                float are=Wa_re[i][oo], aim=Wa_im[i][oo];
                float bre=Wb_re[i][oo], bim=Wb_im[i][oo];
                pre[q] = fmaf(fre, are, fmaf(-fim, aim, pre[q]));
                pim[q] = fmaf(fre, aim, fmaf( fim, are, pim[q]));
                qre[q] = fmaf(fre, bre, fmaf(-fim, bim, qre[q]));
                qim[q] = fmaf(fre, bim, fmaf( fim, bre, qim[q]));
            }
        }
        __syncthreads();
    }
    #pragma unroll
    for (int q=0;q<4;q++){
        int o = og*8 + half*4 + q;
        float g = gate[b*128+o];
        float xre = g*pre[q] + (1.f-g)*qre[q];
        float xim = g*pim[q] + (1.f-g)*qim[q];
        float s = (f==0) ? (1.0f/4096.0f) : (2.0f/4096.0f);
        xre *= s; xim *= s;
        if (f==0) xim = 0.f;
        size_t base = ((size_t)(b*128+o))*256 + 2*f;
        _Float16 h1,l1; split_f16(xre,h1,l1); Xh[base]=h1;   Xl[base]=l1;
        _Float16 h2,l2; split_f16(xim,h2,l2); Xh[base+1]=h2; Xl[base+1]=l2;
    }
}

// ---------------- fused in-place irfft + conv + bias + gelu (MFMA, fp16 split) ----------------
__global__ __launch_bounds__(256) void k_flayer(
    const _Float16* __restrict__ Xh, const _Float16* __restrict__ Xl,
    const _Float16* __restrict__ Tih, const _Float16* __restrict__ Til,
    const float* __restrict__ convW, const float* __restrict__ convB,
    float* __restrict__ h, int layer, int applyGelu){
    __shared__ char smem[55296];
    _Float16 (*Bch)[136] = (_Float16(*)[136])(smem);            // 17,408 B
    _Float16 (*Bcl)[136] = (_Float16(*)[136])(smem + 17408);    // 17,408 B
    _Float16 (*Bsh)[40]  = (_Float16(*)[40])(smem);             // phase-2 reuse
    _Float16 (*Bsl)[40]  = (_Float16(*)[40])(smem + 5120);
    _Float16 (*Ash)[40]  = (_Float16(*)[40])(smem + 34816);
    _Float16 (*Asl)[40]  = (_Float16(*)[40])(smem + 45056);
    int n0 = blockIdx.x*64;
    int b  = blockIdx.y;
    int tid = threadIdx.x;
    int lane = tid & 63, w = tid >> 6;
    int l15 = lane & 15, l4 = lane >> 4;
    int wr = w*32;
    f32x4 acc[2][4] = {}; f32x4 acc2[2][4] = {};
    // stage transposed h tile: Bch[n][c]
    {
        int cpair = tid >> 3;          // 0..31
        int seg   = tid & 7;           // n-segment of 8
        #pragma unroll
        for (int p=0;p<2;p++){
            int c = p*64 + cpair*2;
            const float* r0 = &h[((size_t)(b*128+c))*4096 + n0 + seg*8];
            const float* r1 = r0 + 4096;
            float4 x00 = *reinterpret_cast<const float4*>(r0);
            float4 x01 = *reinterpret_cast<const float4*>(r0+4);
            float4 x10 = *reinterpret_cast<const float4*>(r1);
            float4 x11 = *reinterpret_cast<const float4*>(r1+4);
            float v0[8]={x00.x,x00.y,x00.z,x00.w,x01.x,x01.y,x01.z,x01.w};
            float v1[8]={x10.x,x10.y,x10.z,x10.w,x11.x,x11.y,x11.z,x11.w};
            #pragma unroll
            for (int j=0;j<8;j++){
                int n = seg*8+j;
                _Float16 h0,l0,h1,l1;
                split_f16(v0[j],h0,l0);
                split_f16(v1[j],h1,l1);
                Bch[n][c] = h0; Bch[n][c+1] = h1;
                Bcl[n][c] = l0; Bcl[n][c+1] = l1;
            }
        }
    }
    __syncthreads();
    int so2 = tid >> 2, sseg = tid & 3;
    // phase 1: pointwise conv, K=128
    const float* cw = convW + (size_t)layer*16384;
    for (int k0=0;k0<128;k0+=32){
        #pragma unroll
        for (int p=0;p<2;p++){
            int o = p*64 + so2;
            const float* wp = &cw[(size_t)o*128 + k0 + sseg*8];
            float4 w0 = *reinterpret_cast<const float4*>(wp);
            float4 w1 = *reinterpret_cast<const float4*>(wp+4);
            float wv[8]={w0.x,w0.y,w0.z,w0.w,w1.x,w1.y,w1.z,w1.w};
            half8 vh,vl;
            #pragma unroll
            for (int j=0;j<8;j++){ _Float16 hi,lo; split_f16(wv[j],hi,lo); vh[j]=hi; vl[j]=lo; }
            *reinterpret_cast<half8*>(&Ash[o][sseg*8]) = vh;
            *reinterpret_cast<half8*>(&Asl[o][sseg*8]) = vl;
        }
        __syncthreads();
        half8 ah[2],al[2],bh[4],bl[4];
        #pragma unroll
        for (int i=0;i<2;i++){
            ah[i] = *reinterpret_cast<const half8*>(&Ash[wr+i*16+l15][l4*8]);
            al[i] = *reinterpret_cast<const half8*>(&Asl[wr+i*16+l15][l4*8]);
        }
        #pragma unroll
        for (int j=0;j<4;j++){
            bh[j] = *reinterpret_cast<const half8*>(&Bch[j*16+l15][k0+l4*8]);
            bl[j] = *reinterpret_cast<const half8*>(&Bcl[j*16+l15][k0+l4*8]);
        }
        #pragma unroll
        for (int i=0;i<2;i++)
            #pragma unroll
            for (int j=0;j<4;j++){
                acc[i][j]  = __builtin_amdgcn_mfma_f32_16x16x32_f16(ah[i], bh[j], acc[i][j], 0,0,0);
                acc2[i][j] = __builtin_amdgcn_mfma_f32_16x16x32_f16(ah[i], bl[j], acc2[i][j],0,0,0);
                acc2[i][j] = __builtin_amdgcn_mfma_f32_16x16x32_f16(al[i], bh[j], acc2[i][j],0,0,0);
            }
        __syncthreads();
    }
    // phase 2: irfft, K=256
    for (int k0=0;k0<256;k0+=32){
        #pragma unroll
        for (int p=0;p<2;p++){
            int o = p*64 + so2;
            size_t xi = ((size_t)(b*128+o))*256 + k0 + sseg*8;
            *reinterpret_cast<half8*>(&Ash[o][sseg*8]) = *reinterpret_cast<const half8*>(&Xh[xi]);
            *reinterpret_cast<half8*>(&Asl[o][sseg*8]) = *reinterpret_cast<const half8*>(&Xl[xi]);
        }
        {
            size_t ti = ((size_t)(n0+so2))*256 + k0 + sseg*8;
            *reinterpret_cast<half8*>(&Bsh[so2][sseg*8]) = *reinterpret_cast<const half8*>(&Tih[ti]);
            *reinterpret_cast<half8*>(&Bsl[so2][sseg*8]) = *reinterpret_cast<const half8*>(&Til[ti]);
        }
        __syncthreads();
        half8 ah[2],al[2],bh[4],bl[4];
        #pragma unroll
        for (int i=0;i<2;i++){
            ah[i] = *reinterpret_cast<const half8*>(&Ash[wr+i*16+l15][l4*8]);
            al[i] = *reinterpret_cast<const half8*>(&Asl[wr+i*16+l15][l4*8]);
        }
        #pragma unroll
        for (int j=0;j<4;j++){
            bh[j] = *reinterpret_cast<const half8*>(&Bsh[j*16+l15][l4*8]);
            bl[j] = *reinterpret_cast<const half8*>(&Bsl[j*16+l15][l4*8]);
        }
        #pragma unroll
        for (int i=0;i<2;i++)
            #pragma unroll
            for (int j=0;j<4;j++){
                acc[i][j]  = __builtin_amdgcn_mfma_f32_16x16x32_f16(ah[i], bh[j], acc[i][j], 0,0,0);
                acc2[i][j] = __builtin_amdgcn_mfma_f32_16x16x32_f16(ah[i], bl[j], acc2[i][j],0,0,0);
                acc2[i][j] = __builtin_amdgcn_mfma_f32_16x16x32_f16(al[i], bh[j], acc2[i][j],0,0,0);
            }
        __syncthreads();
    }
    // epilogue
    #pragma unroll
    for (int i=0;i<2;i++)
        #pragma unroll
        for (int j=0;j<4;j++)
            #pragma unroll
            for (int r=0;r<4;r++){
                int o = wr + i*16 + l4*4 + r;
                int n = n0 + j*16 + l15;
                float v = acc[i][j][r] + acc2[i][j][r]*LO_INV + convB[layer*128+o];
                if (applyGelu) v = gelu_f(v);
                h[((size_t)(b*128+o))*4096 + n] = v;
            }
}

// ---------------- head (MFMA): out[b][n] = fc2 . gelu(fc1 . h[:,n] + b1) + b2 ----------------
__global__ __launch_bounds__(256) void k_head(const float* __restrict__ h,
        const float* __restrict__ fc1W, const float* __restrict__ fc1b,
        const float* __restrict__ fc2W, const float* __restrict__ fc2b,
        float* __restrict__ out){
    __shared__ _Float16 Bch[64][136], Bcl[64][136];   // h tile transposed [n][c]
    __shared__ _Float16 Ash[128][40], Asl[128][40];   // fc1W K-chunk
    __shared__ float red[16][64];
    int n0 = blockIdx.x*64;
    int b  = blockIdx.y;
    int tid = threadIdx.x;
    int lane = tid & 63, w = tid >> 6;
    int l15 = lane & 15, l4 = lane >> 4;
    int wr = w*32;
    f32x4 acc[2][4] = {}; f32x4 acc2[2][4] = {};
    // stage transposed h tile
    {
        int cpair = tid >> 3;
        int seg   = tid & 7;
        #pragma unroll
        for (int p=0;p<2;p++){
            int c = p*64 + cpair*2;
            const float* r0 = &h[((size_t)(b*128+c))*4096 + n0 + seg*8];
            const float* r1 = r0 + 4096;
            float4 x00 = *reinterpret_cast<const float4*>(r0);
            float4 x01 = *reinterpret_cast<const float4*>(r0+4);
            float4 x10 = *reinterpret_cast<const float4*>(r1);
            float4 x11 = *reinterpret_cast<const float4*>(r1+4);
            float v0[8]={x00.x,x00.y,x00.z,x00.w,x01.x,x01.y,x01.z,x01.w};
            float v1[8]={x10.x,x10.y,x10.z,x10.w,x11.x,x11.y,x11.z,x11.w};
            #pragma unroll
            for (int j=0;j<8;j++){
                int n = seg*8+j;
                _Float16 h0,l0,h1,l1;
                split_f16(v0[j],h0,l0);
                split_f16(v1[j],h1,l1);
                Bch[n][c] = h0; Bch[n][c+1] = h1;
                Bcl[n][c] = l0; Bcl[n][c+1] = l1;
            }
        }
    }
    __syncthreads();
    int so2 = tid >> 2, sseg = tid & 3;
    // tmp[j][n] = fc1W . h  (K=128, split-f16, 3 MFMA)
    for (int k0=0;k0<128;k0+=32){
        #pragma unroll
        for (int p=0;p<2;p++){
            int o = p*64 + so2;
            const float* wp = &fc1W[(size_t)o*128 + k0 + sseg*8];
            float4 w0 = *reinterpret_cast<const float4*>(wp);
            float4 w1 = *reinterpret_cast<const float4*>(wp+4);
            float wv[8]={w0.x,w0.y,w0.z,w0.w,w1.x,w1.y,w1.z,w1.w};
            half8 vh,vl;
            #pragma unroll
            for (int j=0;j<8;j++){ _Float16 hi,lo; split_f16(wv[j],hi,lo); vh[j]=hi; vl[j]=lo; }
            *reinterpret_cast<half8*>(&Ash[o][sseg*8]) = vh;
            *reinterpret_cast<half8*>(&Asl[o][sseg*8]) = vl;
        }
        __syncthreads();
        half8 ah[2],al[2],bh[4],bl[4];
        #pragma unroll
        for (int i=0;i<2;i++){
            ah[i] = *reinterpret_cast<const half8*>(&Ash[wr+i*16+l15][l4*8]);
            al[i] = *reinterpret_cast<const half8*>(&Asl[wr+i*16+l15][l4*8]);
        }
        #pragma unroll
        for (int j=0;j<4;j++){
            bh[j] = *reinterpret_cast<const half8*>(&Bch[j*16+l15][k0+l4*8]);
            bl[j] = *reinterpret_cast<const half8*>(&Bcl[j*16+l15][k0+l4*8]);
        }
        #pragma unroll
        for (int i=0;i<2;i++)
            #pragma unroll
            for (int j=0;j<4;j++){
                acc[i][j]  = __builtin_amdgcn_mfma_f32_16x16x32_f16(ah[i], bh[j], acc[i][j], 0,0,0);
                acc2[i][j] = __builtin_amdgcn_mfma_f32_16x16x32_f16(ah[i], bl[j], acc2[i][j],0,0,0);
                acc2[i][j] = __builtin_amdgcn_mfma_f32_16x16x32_f16(al[i], bh[j], acc2[i][j],0,0,0);
            }
        __syncthreads();
    }
    // epilogue: bias + gelu + fc2-weighted partial over this thread's 8 j values
    float part[4];
    #pragma unroll
    for (int j=0;j<4;j++) part[j] = 0.f;
    #pragma unroll
    for (int i=0;i<2;i++){
        #pragma unroll
        for (int r=0;r<4;r++){
            int jj = wr + i*16 + l4*4 + r;
            float b1 = fc1b[jj];
            float w2 = fc2W[jj];
            #pragma unroll
            for (int j=0;j<4;j++){
                float v = acc[i][j][r] + acc2[i][j][r]*LO_INV + b1;
                part[j] = fmaf(w2, gelu_f(v), part[j]);
            }
        }
    }
    #pragma unroll
    for (int j=0;j<4;j++) red[w*4+l4][j*16+l15] = part[j];
    __syncthreads();
    if (tid < 64){
        float s = fc2b[0];
        #pragma unroll
        for (int r=0;r<16;r++) s += red[r][tid];
        out[((size_t)b<<12) + n0 + tid] = s;
    }
}

extern "C" void kernel_launch(void* const* d_in, const int* in_sizes, int n_in,
                              void* d_out, int out_size, void* d_ws, size_t ws_size,
                              hipStream_t stream) {
    const float* x     = (const float*)d_in[0];
    const float* fc0W  = (const float*)d_in[1];
    const float* fc0b  = (const float*)d_in[2];
    const float* gateW = (const float*)d_in[3];
    const float* gateB = (const float*)d_in[4];
    const float* wAre  = (const float*)d_in[5];
    const float* wAim  = (const float*)d_in[6];
    const float* wBre  = (const float*)d_in[7];
    const float* wBim  = (const float*)d_in[8];
    const float* convW = (const float*)d_in[9];
    const float* convB = (const float*)d_in[10];
    const float* fc1W  = (const float*)d_in[11];
    const float* fc1b  = (const float*)d_in[12];
    const float* fc2W  = (const float*)d_in[13];
    const float* fc2b  = (const float*)d_in[14];
    float* out = (float*)d_out;
    char*  wsb = (char*)d_ws;

    float* F    = (float*)(wsb + BY_F);
    float* wsum = (float*)(wsb + BY_wsum);
    float* Wcre = (float*)(wsb + BY_Wcre);
    float* Wcim = (float*)(wsb + BY_Wcim);
    float* wl   = (float*)(wsb + BY_wl);
    float* wr   = (float*)(wsb + BY_wr);
    int*   li   = (int*)(wsb + BY_li);
    float* magp = (float*)(wsb + BY_magp);
    float* gate = (float*)(wsb + BY_gate);
    float* h    = (float*)(wsb + BY_h);
    _Float16* Tfh = (_Float16*)(wsb + BY_Tfh);
    _Float16* Tfl = (_Float16*)(wsb + BY_Tfl);
    _Float16* Tih = (_Float16*)(wsb + BY_Tih);
    _Float16* Til = (_Float16*)(wsb + BY_Til);
    _Float16* Xh  = (_Float16*)(wsb + BY_Xh);
    _Float16* Xl  = (_Float16*)(wsb + BY_Xl);

    k_tables<<<4096, 256, 0, stream>>>(Tfh, Tfl, Tih, Til);
    k_cft_tables<<<160, 128, 0, stream>>>(Wcre, Wcim, wl, wr, li);
    k_wsum<<<dim3(16384,4), 256, 0, stream>>>(wAre, wAim, wBre, wBim, wsum);
    k_h0<<<131072, 256, 0, stream>>>(x, fc0W, fc0b, h);

    for (int layer=0; layer<4; layer++){
        k_cft<<<dim3(64,8), 128, 0, stream>>>(h, Wcre, Wcim, wl, wr, li, magp);
        k_gate<<<64, 128, 0, stream>>>(magp, gateW, gateB, gate, layer);
        k_fdft<<<512, 256, 0, stream>>>(h, Tfh, Tfl, F);
        k_modemix<<<dim3(64,16), 256, 0, stream>>>(F, wsum, gate, Xh, Xl, layer);
        k_flayer<<<dim3(64,64), 256, 0, stream>>>(Xh, Xl, Tih, Til, convW, convB,
                                                  h, layer, layer<3 ? 1:0);
    }
    k_head<<<dim3(64,64), 256, 0, stream>>>(h, fc1W, fc1b, fc2W, fc2b, out);
    (void)in_sizes; (void)n_in; (void)out_size; (void)ws_size;
}

// Round 5
// 1686.188 us; speedup vs baseline: 2.6409x; 1.0054x over previous
//
#include <hip/hip_runtime.h>
#include <math.h>

#define B_SZ 64
#define WID 128
#define NPT 4096
#define MODES 128
#define LSEG 20
#define MCH 8
#define LM 160   // LSEG*MCH

typedef _Float16 half8 __attribute__((ext_vector_type(8)));
typedef float f32x4 __attribute__((ext_vector_type(4)));

#define LO_SCALE 2048.0f
#define LO_INV   (1.0f/2048.0f)

// ---------------- workspace layout (bytes), total ~161.3 MB ----------------
static constexpr size_t BY_F    = 0;                       // fp32 [8192][256]
static constexpr size_t BY_wsum = BY_F + 8388608;          // fp32 [4][4][128][128]
static constexpr size_t BY_Wcre = BY_wsum + 1048576;       // fp32 [160][128]
static constexpr size_t BY_Wcim = BY_Wcre + 81920;
static constexpr size_t BY_wl   = BY_Wcim + 81920;         // fp32 [160] (pad)
static constexpr size_t BY_wr   = BY_wl + 1024;
static constexpr size_t BY_li   = BY_wr + 1024;            // int [160]
static constexpr size_t BY_magp = BY_li + 1024;            // fp32 [64][8][128]
static constexpr size_t BY_gate = BY_magp + 262144;        // fp32 [64][128]
static constexpr size_t BY_hh   = BY_gate + 32768;         // f16 [64][128][4096] split-hi
static constexpr size_t BY_hl   = BY_hh + 67108864;        // f16 split-lo
static constexpr size_t BY_Tfh  = BY_hl + 67108864;        // f16 [256][4096]
static constexpr size_t BY_Tfl  = BY_Tfh + 2097152;
static constexpr size_t BY_Tih  = BY_Tfl + 2097152;        // f16 [4096][256]
static constexpr size_t BY_Til  = BY_Tih + 2097152;
static constexpr size_t BY_Xh   = BY_Til + 2097152;        // f16 [64][128][256]
static constexpr size_t BY_Xl   = BY_Xh + 4194304;
static constexpr size_t BY_cWh  = BY_Xl + 4194304;         // f16 [4][128][128]
static constexpr size_t BY_cWl  = BY_cWh + 131072;
static constexpr size_t BY_f1h  = BY_cWl + 131072;         // f16 [128][128]
static constexpr size_t BY_f1l  = BY_f1h + 32768;
static constexpr size_t BY_end  = BY_f1l + 32768;

__device__ __forceinline__ float gelu_f(float x){
    return 0.5f*x*(1.0f+erff(x*0.70710678118654752f));
}
__device__ __forceinline__ void split_f16(float v, _Float16& hi, _Float16& lo){
    hi = (_Float16)v;
    lo = (_Float16)((v - (float)hi)*LO_SCALE);
}

// ---------------- tables (split f16) ----------------
__global__ void k_tables(_Float16* __restrict__ Tfh, _Float16* __restrict__ Tfl,
                         _Float16* __restrict__ Tih, _Float16* __restrict__ Til){
    int idx = blockIdx.x*256 + threadIdx.x;   // 4096*256
    int n = idx >> 8, k2 = idx & 255;
    int f = k2 >> 1;
    int m = (n*f) & 4095;
    double th = (double)m * (3.14159265358979323846/2048.0);
    double s, c; sincos(th, &s, &c);
    float vf = (k2&1) ? (float)(-s) : (float)c;
    _Float16 h1,l1; split_f16(vf, h1, l1);
    Tfh[(size_t)k2*4096 + n] = h1;
    Tfl[(size_t)k2*4096 + n] = l1;
    float vi;
    if (k2 == 0)      vi = 1.0f;
    else if (k2 == 1) vi = 0.0f;
    else              vi = vf;
    _Float16 h2,l2; split_f16(vi, h2, l2);
    Tih[(size_t)n*256 + k2] = h2;
    Til[(size_t)n*256 + k2] = l2;
}

__global__ void k_cft_tables(float* __restrict__ Wre, float* __restrict__ Wim,
                             float* __restrict__ wl, float* __restrict__ wr,
                             int* __restrict__ li){
    int idx = blockIdx.x*128 + threadIdx.x;   // 160*128
    if (idx >= LM*MODES) return;
    int lm = idx >> 7;  int f = idx & 127;
    int l = lm / MCH, m = lm % MCH;
    const double PI = 3.14159265358979323846;
    double nodes[8], Tm[8];
    #pragma unroll
    for (int j=0;j<8;j++){
        nodes[j] = -cos((2.0*j+1.0)*PI/16.0);
        Tm[j] = cos((double)m * acos(nodes[j]));
    }
    double wp = (double)f * PI * 0.05;
    double cwre=0.0, cwim=0.0;
    #pragma unroll
    for (int j=0;j<8;j++){
        double sj, cj; sincos(nodes[j]*wp, &sj, &cj);
        cwre += Tm[j]*cj;
        cwim -= Tm[j]*sj;
    }
    cwre *= 0.025; cwim *= 0.025;
    int r = (f*l) % 20;
    double sa = 2.0*PI*(double)r/20.0;
    double shre = cos(sa), shim = -sin(sa);
    Wre[lm*128+f] = (float)(shre*cwre - shim*cwim);
    Wim[lm*128+f] = (float)(shre*cwim + shim*cwre);
    if (f == 0){
        double v = (double)l/20.0 + 0.025*(nodes[m]+1.0);
        int rr = (int)ceil(v*4095.0);
        if (rr > 4095) rr = 4095;
        if (rr < 1) rr = 1;
        int le = rr-1;
        double tl = (double)le/4095.0, tr = (double)rr/4095.0;
        double wrv = (v - tl)/(tr - tl);
        li[lm] = le;
        wl[lm] = (float)(1.0 - wrv);
        wr[lm] = (float)wrv;
    }
}

// sum wA/wB over mode axis
__global__ void k_wsum(const float* __restrict__ wAre, const float* __restrict__ wAim,
                       const float* __restrict__ wBre, const float* __restrict__ wBim,
                       float* __restrict__ out){
    int row  = blockIdx.x*4 + (threadIdx.x>>6);
    int lane = threadIdx.x & 63;
    const float* src = (blockIdx.y==0)?wAre:(blockIdx.y==1)?wAim:(blockIdx.y==2)?wBre:wBim;
    float v = src[(size_t)row*128 + lane] + src[(size_t)row*128 + 64 + lane];
    #pragma unroll
    for (int o=32;o>0;o>>=1) v += __shfl_down(v, o);
    if (lane==0) out[(size_t)blockIdx.y*65536 + row] = v;
}

// pre-split conv & fc1 weights
__global__ void k_wsplit(const float* __restrict__ convW, const float* __restrict__ fc1W,
                         _Float16* __restrict__ cWh, _Float16* __restrict__ cWl,
                         _Float16* __restrict__ f1h, _Float16* __restrict__ f1l){
    int idx = blockIdx.x*256 + threadIdx.x;   // 81920
    if (idx < 65536){
        _Float16 hi,lo; split_f16(convW[idx], hi, lo);
        cWh[idx]=hi; cWl[idx]=lo;
    } else {
        int j = idx - 65536;
        _Float16 hi,lo; split_f16(fc1W[j], hi, lo);
        f1h[j]=hi; f1l[j]=lo;
    }
}

// ---------------- lift: write split h ----------------
__global__ void k_h0(const float* __restrict__ x, const float* __restrict__ w0,
                     const float* __restrict__ b0,
                     _Float16* __restrict__ hh, _Float16* __restrict__ hl){
    int idx = blockIdx.x*256 + threadIdx.x;  // 64*128*512
    int n8 = idx & 511;
    int w  = (idx >> 9) & 127;
    int b  = idx >> 16;
    int n0 = n8*8;
    float w00 = w0[w*2], w01 = w0[w*2+1], bb = b0[w];
    const float* xr = &x[((size_t)b<<12) + n0];
    float4 x0 = *reinterpret_cast<const float4*>(xr);
    float4 x1 = *reinterpret_cast<const float4*>(xr+4);
    float xv[8]={x0.x,x0.y,x0.z,x0.w,x1.x,x1.y,x1.z,x1.w};
    half8 vh, vl;
    #pragma unroll
    for (int q=0;q<8;q++){
        float g = (float)(n0+q) * (1.0f/4095.0f);
        float v = xv[q]*w00 + g*w01 + bb;
        _Float16 hi,lo; split_f16(v,hi,lo);
        vh[q]=hi; vl[q]=lo;
    }
    size_t o = ((size_t)(b*128+w))*4096 + n0;
    *reinterpret_cast<half8*>(&hh[o]) = vh;
    *reinterpret_cast<half8*>(&hl[o]) = vl;
}

// ---------------- CFT magnitude ----------------
__global__ void k_cft(const _Float16* __restrict__ hh, const _Float16* __restrict__ hl,
                      const float* __restrict__ Wre, const float* __restrict__ Wim,
                      const float* __restrict__ wl, const float* __restrict__ wr,
                      const int* __restrict__ li, float* __restrict__ magp){
    int b = blockIdx.x, cg = blockIdx.y;
    int f = threadIdx.x;   // 128
    __shared__ float sig[LM];
    __shared__ float swl[LM], swr[LM];
    __shared__ int   sli[LM];
    for (int s=f; s<LM; s+=128){ swl[s]=wl[s]; swr[s]=wr[s]; sli[s]=li[s]; }
    __syncthreads();
    float acc = 0.f;
    for (int cc=0; cc<16; cc++){
        int c = cg*16 + cc;
        const _Float16* rh = hh + ((size_t)(b*128+c))*4096;
        const _Float16* rl = hl + ((size_t)(b*128+c))*4096;
        for (int s=f; s<LM; s+=128){
            int le = sli[s];
            float v0 = (float)rh[le]   + (float)rl[le]*LO_INV;
            float v1 = (float)rh[le+1] + (float)rl[le+1]*LO_INV;
            sig[s] = swl[s]*v0 + swr[s]*v1;
        }
        __syncthreads();
        float re=0.f, im=0.f;
        #pragma unroll 8
        for (int s=0;s<LM;s++){
            float sv = sig[s];
            re = fmaf(sv, Wre[s*128+f], re);
            im = fmaf(sv, Wim[s*128+f], im);
        }
        acc += sqrtf(re*re+im*im);
        __syncthreads();
    }
    magp[(b*8+cg)*128 + f] = acc;
}

__global__ void k_gate(const float* __restrict__ magp, const float* __restrict__ gW,
                       const float* __restrict__ gB, float* __restrict__ gate, int layer){
    int b = blockIdx.x, w = threadIdx.x;
    __shared__ float ms[128];
    float s = 0.f;
    #pragma unroll
    for (int g=0; g<8; g++) s += magp[(b*8+g)*128 + w];
    ms[w] = s * (1.0f/128.0f);
    __syncthreads();
    const float* gwr = gW + ((size_t)layer*128 + w)*128;
    float a = gB[layer*128 + w];
    #pragma unroll 8
    for (int fq=0; fq<128; fq++) a = fmaf(ms[fq], gwr[fq], a);
    gate[b*128+w] = 1.0f/(1.0f+expf(-a));
}

// ---------------- forward DFT (MFMA): F = h[8192][4096] x Tf^T ----------------
__global__ __launch_bounds__(256) void k_fdft(
        const _Float16* __restrict__ hh, const _Float16* __restrict__ hl,
        const _Float16* __restrict__ Tfh, const _Float16* __restrict__ Tfl,
        float* __restrict__ F){
    __shared__ _Float16 Ah[64][40], Al[64][40], Bh[64][40], Bl[64][40];
    int id = blockIdx.x;
    int swz = (id & 7)*64 + (id >> 3);        // bijective for 512
    int bx = swz & 3, by = swz >> 2;
    int col0 = bx*64, row0 = by*64;
    int tid = threadIdx.x;
    int lane = tid & 63, w = tid >> 6;
    int wr = (w>>1)*32, wc = (w&1)*32;
    int l15 = lane & 15, l4 = lane >> 4;
    f32x4 acc[2][2] = {}; f32x4 acc2[2][2] = {};
    int srow = tid >> 2, sseg = tid & 3;
    const size_t arow = (size_t)(row0 + srow)*4096;
    const size_t brow = (size_t)(col0 + srow)*4096;
    for (int k0 = 0; k0 < 4096; k0 += 32){
        *reinterpret_cast<half8*>(&Ah[srow][sseg*8]) =
            *reinterpret_cast<const half8*>(&hh[arow + k0 + sseg*8]);
        *reinterpret_cast<half8*>(&Al[srow][sseg*8]) =
            *reinterpret_cast<const half8*>(&hl[arow + k0 + sseg*8]);
        *reinterpret_cast<half8*>(&Bh[srow][sseg*8]) =
            *reinterpret_cast<const half8*>(&Tfh[brow + k0 + sseg*8]);
        *reinterpret_cast<half8*>(&Bl[srow][sseg*8]) =
            *reinterpret_cast<const half8*>(&Tfl[brow + k0 + sseg*8]);
        __syncthreads();
        half8 fah[2], fal[2], fbh[2], fbl[2];
        #pragma unroll
        for (int i=0;i<2;i++){
            fah[i] = *reinterpret_cast<const half8*>(&Ah[wr + i*16 + l15][l4*8]);
            fal[i] = *reinterpret_cast<const half8*>(&Al[wr + i*16 + l15][l4*8]);
            fbh[i] = *reinterpret_cast<const half8*>(&Bh[wc + i*16 + l15][l4*8]);
            fbl[i] = *reinterpret_cast<const half8*>(&Bl[wc + i*16 + l15][l4*8]);
        }
        #pragma unroll
        for (int i=0;i<2;i++)
            #pragma unroll
            for (int j=0;j<2;j++){
                acc[i][j]  = __builtin_amdgcn_mfma_f32_16x16x32_f16(fah[i], fbh[j], acc[i][j], 0,0,0);
                acc2[i][j] = __builtin_amdgcn_mfma_f32_16x16x32_f16(fah[i], fbl[j], acc2[i][j],0,0,0);
                acc2[i][j] = __builtin_amdgcn_mfma_f32_16x16x32_f16(fal[i], fbh[j], acc2[i][j],0,0,0);
            }
        __syncthreads();
    }
    #pragma unroll
    for (int i=0;i<2;i++)
        #pragma unroll
        for (int j=0;j<2;j++)
            #pragma unroll
            for (int r=0;r<4;r++){
                int row = row0 + wr + i*16 + l4*4 + r;
                int col = col0 + wc + j*16 + l15;
                F[(size_t)row*256 + col] = acc[i][j][r] + acc2[i][j][r]*LO_INV;
            }
}

// ---------------- mode mix: X = g*(F.wA) + (1-g)*(F.wB), scaled, split ----------------
__global__ __launch_bounds__(256) void k_modemix(const float* __restrict__ F,
        const float* __restrict__ wsum, const float* __restrict__ gate,
        _Float16* __restrict__ Xh, _Float16* __restrict__ Xl, int layer){
    int b = blockIdx.x, og = blockIdx.y;
    __shared__ float Fs[16][256];
    __shared__ float Wa_re[128][8], Wa_im[128][8], Wb_re[128][8], Wb_im[128][8];
    int tid = threadIdx.x;
    for (int e=tid; e<1024; e+=256){
        int i = e>>3, oo = e&7;
        size_t base = ((size_t)layer*128 + i)*128 + og*8 + oo;
        Wa_re[i][oo] = wsum[0*65536 + base];
        Wa_im[i][oo] = wsum[1*65536 + base];
        Wb_re[i][oo] = wsum[2*65536 + base];
        Wb_im[i][oo] = wsum[3*65536 + base];
    }
    int f = tid & 127, half = tid >> 7;
    float pre[4]={},pim[4]={},qre[4]={},qim[4]={};
    for (int i0=0;i0<128;i0+=16){
        for (int e=tid; e<4096; e+=256){
            int ii = e >> 8, k2 = e & 255;
            Fs[ii][k2] = F[((size_t)(b*128 + i0+ii))*256 + k2];
        }
        __syncthreads();
        #pragma unroll
        for (int ii=0; ii<16; ii++){
            float fre = Fs[ii][2*f], fim = Fs[ii][2*f+1];
            int i = i0+ii;
            #pragma unroll
            for (int q=0;q<4;q++){
                int oo = half*4+q;
                float are=Wa_re[i][oo], aim=Wa_im[i][oo];
                float bre=Wb_re[i][oo], bim=Wb_im[i][oo];
                pre[q] = fmaf(fre, are, fmaf(-fim, aim, pre[q]));
                pim[q] = fmaf(fre, aim, fmaf( fim, are, pim[q]));
                qre[q] = fmaf(fre, bre, fmaf(-fim, bim, qre[q]));
                qim[q] = fmaf(fre, bim, fmaf( fim, bre, qim[q]));
            }
        }
        __syncthreads();
    }
    #pragma unroll
    for (int q=0;q<4;q++){
        int o = og*8 + half*4 + q;
        float g = gate[b*128+o];
        float xre = g*pre[q] + (1.f-g)*qre[q];
        float xim = g*pim[q] + (1.f-g)*qim[q];
        float s = (f==0) ? (1.0f/4096.0f) : (2.0f/4096.0f);
        xre *= s; xim *= s;
        if (f==0) xim = 0.f;
        size_t base = ((size_t)(b*128+o))*256 + 2*f;
        _Float16 h1,l1; split_f16(xre,h1,l1); Xh[base]=h1;   Xl[base]=l1;
        _Float16 h2,l2; split_f16(xim,h2,l2); Xh[base+1]=h2; Xl[base+1]=l2;
    }
}

// ---------------- fused in-place irfft + conv + bias + gelu (MFMA) ----------------
__global__ __launch_bounds__(256) void k_flayer(
    const _Float16* __restrict__ Xh, const _Float16* __restrict__ Xl,
    const _Float16* __restrict__ Tih, const _Float16* __restrict__ Til,
    const _Float16* __restrict__ cWh, const _Float16* __restrict__ cWl,
    const float* __restrict__ convB,
    _Float16* __restrict__ hh, _Float16* __restrict__ hl,
    int layer, int applyGelu){
    __shared__ char smem[55296];
    _Float16 (*Bch)[136] = (_Float16(*)[136])(smem);            // 17,408 B
    _Float16 (*Bcl)[136] = (_Float16(*)[136])(smem + 17408);
    _Float16 (*Bsh)[40]  = (_Float16(*)[40])(smem);             // phase-2 reuse
    _Float16 (*Bsl)[40]  = (_Float16(*)[40])(smem + 5120);
    _Float16 (*Ash)[40]  = (_Float16(*)[40])(smem + 34816);
    _Float16 (*Asl)[40]  = (_Float16(*)[40])(smem + 45056);
    int n0 = blockIdx.x*64;
    int b  = blockIdx.y;
    int tid = threadIdx.x;
    int lane = tid & 63, w = tid >> 6;
    int l15 = lane & 15, l4 = lane >> 4;
    int wr = w*32;
    f32x4 acc[2][4] = {}; f32x4 acc2[2][4] = {};
    // stage transposed h tile: lane-per-channel (conflict-free u16 writes)
    {
        int c = tid & 127, nh = tid >> 7;
        const _Float16* rh = hh + ((size_t)(b*128+c))*4096 + n0 + nh*32;
        const _Float16* rl = hl + ((size_t)(b*128+c))*4096 + n0 + nh*32;
        #pragma unroll
        for (int j=0;j<4;j++){
            half8 vhv = *reinterpret_cast<const half8*>(rh + j*8);
            half8 vlv = *reinterpret_cast<const half8*>(rl + j*8);
            #pragma unroll
            for (int q=0;q<8;q++){
                int n = nh*32 + j*8 + q;
                Bch[n][c] = vhv[q];
                Bcl[n][c] = vlv[q];
            }
        }
    }
    __syncthreads();
    int so2 = tid >> 2, sseg = tid & 3;
    // phase 1: pointwise conv, K=128
    const _Float16* cwh = cWh + (size_t)layer*16384;
    const _Float16* cwl = cWl + (size_t)layer*16384;
    for (int k0=0;k0<128;k0+=32){
        #pragma unroll
        for (int p=0;p<2;p++){
            int o = p*64 + so2;
            *reinterpret_cast<half8*>(&Ash[o][sseg*8]) =
                *reinterpret_cast<const half8*>(&cwh[(size_t)o*128 + k0 + sseg*8]);
            *reinterpret_cast<half8*>(&Asl[o][sseg*8]) =
                *reinterpret_cast<const half8*>(&cwl[(size_t)o*128 + k0 + sseg*8]);
        }
        __syncthreads();
        half8 ah[2],al[2],bh[4],bl[4];
        #pragma unroll
        for (int i=0;i<2;i++){
            ah[i] = *reinterpret_cast<const half8*>(&Ash[wr+i*16+l15][l4*8]);
            al[i] = *reinterpret_cast<const half8*>(&Asl[wr+i*16+l15][l4*8]);
        }
        #pragma unroll
        for (int j=0;j<4;j++){
            bh[j] = *reinterpret_cast<const half8*>(&Bch[j*16+l15][k0+l4*8]);
            bl[j] = *reinterpret_cast<const half8*>(&Bcl[j*16+l15][k0+l4*8]);
        }
        #pragma unroll
        for (int i=0;i<2;i++)
            #pragma unroll
            for (int j=0;j<4;j++){
                acc[i][j]  = __builtin_amdgcn_mfma_f32_16x16x32_f16(ah[i], bh[j], acc[i][j], 0,0,0);
                acc2[i][j] = __builtin_amdgcn_mfma_f32_16x16x32_f16(ah[i], bl[j], acc2[i][j],0,0,0);
                acc2[i][j] = __builtin_amdgcn_mfma_f32_16x16x32_f16(al[i], bh[j], acc2[i][j],0,0,0);
            }
        __syncthreads();
    }
    // phase 2: irfft, K=256
    for (int k0=0;k0<256;k0+=32){
        #pragma unroll
        for (int p=0;p<2;p++){
            int o = p*64 + so2;
            size_t xi = ((size_t)(b*128+o))*256 + k0 + sseg*8;
            *reinterpret_cast<half8*>(&Ash[o][sseg*8]) = *reinterpret_cast<const half8*>(&Xh[xi]);
            *reinterpret_cast<half8*>(&Asl[o][sseg*8]) = *reinterpret_cast<const half8*>(&Xl[xi]);
        }
        {
            size_t ti = ((size_t)(n0+so2))*256 + k0 + sseg*8;
            *reinterpret_cast<half8*>(&Bsh[so2][sseg*8]) = *reinterpret_cast<const half8*>(&Tih[ti]);
            *reinterpret_cast<half8*>(&Bsl[so2][sseg*8]) = *reinterpret_cast<const half8*>(&Til[ti]);
        }
        __syncthreads();
        half8 ah[2],al[2],bh[4],bl[4];
        #pragma unroll
        for (int i=0;i<2;i++){
            ah[i] = *reinterpret_cast<const half8*>(&Ash[wr+i*16+l15][l4*8]);
            al[i] = *reinterpret_cast<const half8*>(&Asl[wr+i*16+l15][l4*8]);
        }
        #pragma unroll
        for (int j=0;j<4;j++){
            bh[j] = *reinterpret_cast<const half8*>(&Bsh[j*16+l15][l4*8]);
            bl[j] = *reinterpret_cast<const half8*>(&Bsl[j*16+l15][l4*8]);
        }
        #pragma unroll
        for (int i=0;i<2;i++)
            #pragma unroll
            for (int j=0;j<4;j++){
                acc[i][j]  = __builtin_amdgcn_mfma_f32_16x16x32_f16(ah[i], bh[j], acc[i][j], 0,0,0);
                acc2[i][j] = __builtin_amdgcn_mfma_f32_16x16x32_f16(ah[i], bl[j], acc2[i][j],0,0,0);
                acc2[i][j] = __builtin_amdgcn_mfma_f32_16x16x32_f16(al[i], bh[j], acc2[i][j],0,0,0);
            }
        __syncthreads();
    }
    // epilogue: bias (+gelu), split, write back in place
    #pragma unroll
    for (int i=0;i<2;i++)
        #pragma unroll
        for (int j=0;j<4;j++)
            #pragma unroll
            for (int r=0;r<4;r++){
                int o = wr + i*16 + l4*4 + r;
                int n = n0 + j*16 + l15;
                float v = acc[i][j][r] + acc2[i][j][r]*LO_INV + convB[layer*128+o];
                if (applyGelu) v = gelu_f(v);
                _Float16 hi,lo; split_f16(v,hi,lo);
                size_t oi = ((size_t)(b*128+o))*4096 + n;
                hh[oi] = hi; hl[oi] = lo;
            }
}

// ---------------- head (MFMA) ----------------
__global__ __launch_bounds__(256) void k_head(
        const _Float16* __restrict__ hh, const _Float16* __restrict__ hl,
        const _Float16* __restrict__ f1h, const _Float16* __restrict__ f1l,
        const float* __restrict__ fc1b,
        const float* __restrict__ fc2W, const float* __restrict__ fc2b,
        float* __restrict__ out){
    __shared__ _Float16 Bch[64][136], Bcl[64][136];
    __shared__ _Float16 Ash[128][40], Asl[128][40];
    __shared__ float red[16][64];
    int n0 = blockIdx.x*64;
    int b  = blockIdx.y;
    int tid = threadIdx.x;
    int lane = tid & 63, w = tid >> 6;
    int l15 = lane & 15, l4 = lane >> 4;
    int wr = w*32;
    f32x4 acc[2][4] = {}; f32x4 acc2[2][4] = {};
    {
        int c = tid & 127, nh = tid >> 7;
        const _Float16* rh = hh + ((size_t)(b*128+c))*4096 + n0 + nh*32;
        const _Float16* rl = hl + ((size_t)(b*128+c))*4096 + n0 + nh*32;
        #pragma unroll
        for (int j=0;j<4;j++){
            half8 vhv = *reinterpret_cast<const half8*>(rh + j*8);
            half8 vlv = *reinterpret_cast<const half8*>(rl + j*8);
            #pragma unroll
            for (int q=0;q<8;q++){
                int n = nh*32 + j*8 + q;
                Bch[n][c] = vhv[q];
                Bcl[n][c] = vlv[q];
            }
        }
    }
    __syncthreads();
    int so2 = tid >> 2, sseg = tid & 3;
    for (int k0=0;k0<128;k0+=32){
        #pragma unroll
        for (int p=0;p<2;p++){
            int o = p*64 + so2;
            *reinterpret_cast<half8*>(&Ash[o][sseg*8]) =
                *reinterpret_cast<const half8*>(&f1h[(size_t)o*128 + k0 + sseg*8]);
            *reinterpret_cast<half8*>(&Asl[o][sseg*8]) =
                *reinterpret_cast<const half8*>(&f1l[(size_t)o*128 + k0 + sseg*8]);
        }
        __syncthreads();
        half8 ah[2],al[2],bh[4],bl[4];
        #pragma unroll
        for (int i=0;i<2;i++){
            ah[i] = *reinterpret_cast<const half8*>(&Ash[wr+i*16+l15][l4*8]);
            al[i] = *reinterpret_cast<const half8*>(&Asl[wr+i*16+l15][l4*8]);
        }
        #pragma unroll
        for (int j=0;j<4;j++){
            bh[j] = *reinterpret_cast<const half8*>(&Bch[j*16+l15][k0+l4*8]);
            bl[j] = *reinterpret_cast<const half8*>(&Bcl[j*16+l15][k0+l4*8]);
        }
        #pragma unroll
        for (int i=0;i<2;i++)
            #pragma unroll
            for (int j=0;j<4;j++){
                acc[i][j]  = __builtin_amdgcn_mfma_f32_16x16x32_f16(ah[i], bh[j], acc[i][j], 0,0,0);
                acc2[i][j] = __builtin_amdgcn_mfma_f32_16x16x32_f16(ah[i], bl[j], acc2[i][j],0,0,0);
                acc2[i][j] = __builtin_amdgcn_mfma_f32_16x16x32_f16(al[i], bh[j], acc2[i][j],0,0,0);
            }
        __syncthreads();
    }
    float part[4];
    #pragma unroll
    for (int j=0;j<4;j++) part[j] = 0.f;
    #pragma unroll
    for (int i=0;i<2;i++){
        #pragma unroll
        for (int r=0;r<4;r++){
            int jj = wr + i*16 + l4*4 + r;
            float b1 = fc1b[jj];
            float w2 = fc2W[jj];
            #pragma unroll
            for (int j=0;j<4;j++){
                float v = acc[i][j][r] + acc2[i][j][r]*LO_INV + b1;
                part[j] = fmaf(w2, gelu_f(v), part[j]);
            }
        }
    }
    #pragma unroll
    for (int j=0;j<4;j++) red[w*4+l4][j*16+l15] = part[j];
    __syncthreads();
    if (tid < 64){
        float s = fc2b[0];
        #pragma unroll
        for (int r=0;r<16;r++) s += red[r][tid];
        out[((size_t)b<<12) + n0 + tid] = s;
    }
}

extern "C" void kernel_launch(void* const* d_in, const int* in_sizes, int n_in,
                              void* d_out, int out_size, void* d_ws, size_t ws_size,
                              hipStream_t stream) {
    const float* x     = (const float*)d_in[0];
    const float* fc0W  = (const float*)d_in[1];
    const float* fc0b  = (const float*)d_in[2];
    const float* gateW = (const float*)d_in[3];
    const float* gateB = (const float*)d_in[4];
    const float* wAre  = (const float*)d_in[5];
    const float* wAim  = (const float*)d_in[6];
    const float* wBre  = (const float*)d_in[7];
    const float* wBim  = (const float*)d_in[8];
    const float* convW = (const float*)d_in[9];
    const float* convB = (const float*)d_in[10];
    const float* fc1W  = (const float*)d_in[11];
    const float* fc1b  = (const float*)d_in[12];
    const float* fc2W  = (const float*)d_in[13];
    const float* fc2b  = (const float*)d_in[14];
    float* out = (float*)d_out;
    char*  wsb = (char*)d_ws;

    float* F    = (float*)(wsb + BY_F);
    float* wsum = (float*)(wsb + BY_wsum);
    float* Wcre = (float*)(wsb + BY_Wcre);
    float* Wcim = (float*)(wsb + BY_Wcim);
    float* wl   = (float*)(wsb + BY_wl);
    float* wr   = (float*)(wsb + BY_wr);
    int*   li   = (int*)(wsb + BY_li);
    float* magp = (float*)(wsb + BY_magp);
    float* gate = (float*)(wsb + BY_gate);
    _Float16* hh  = (_Float16*)(wsb + BY_hh);
    _Float16* hl  = (_Float16*)(wsb + BY_hl);
    _Float16* Tfh = (_Float16*)(wsb + BY_Tfh);
    _Float16* Tfl = (_Float16*)(wsb + BY_Tfl);
    _Float16* Tih = (_Float16*)(wsb + BY_Tih);
    _Float16* Til = (_Float16*)(wsb + BY_Til);
    _Float16* Xh  = (_Float16*)(wsb + BY_Xh);
    _Float16* Xl  = (_Float16*)(wsb + BY_Xl);
    _Float16* cWh = (_Float16*)(wsb + BY_cWh);
    _Float16* cWl = (_Float16*)(wsb + BY_cWl);
    _Float16* f1h = (_Float16*)(wsb + BY_f1h);
    _Float16* f1l = (_Float16*)(wsb + BY_f1l);

    k_tables<<<4096, 256, 0, stream>>>(Tfh, Tfl, Tih, Til);
    k_cft_tables<<<160, 128, 0, stream>>>(Wcre, Wcim, wl, wr, li);
    k_wsum<<<dim3(16384,4), 256, 0, stream>>>(wAre, wAim, wBre, wBim, wsum);
    k_wsplit<<<320, 256, 0, stream>>>(convW, fc1W, cWh, cWl, f1h, f1l);
    k_h0<<<16384, 256, 0, stream>>>(x, fc0W, fc0b, hh, hl);

    for (int layer=0; layer<4; layer++){
        k_cft<<<dim3(64,8), 128, 0, stream>>>(hh, hl, Wcre, Wcim, wl, wr, li, magp);
        k_gate<<<64, 128, 0, stream>>>(magp, gateW, gateB, gate, layer);
        k_fdft<<<512, 256, 0, stream>>>(hh, hl, Tfh, Tfl, F);
        k_modemix<<<dim3(64,16), 256, 0, stream>>>(F, wsum, gate, Xh, Xl, layer);
        k_flayer<<<dim3(64,64), 256, 0, stream>>>(Xh, Xl, Tih, Til, cWh, cWl, convB,
                                                  hh, hl, layer, layer<3 ? 1:0);
    }
    k_head<<<dim3(64,64), 256, 0, stream>>>(hh, hl, f1h, f1l, fc1b, fc2W, fc2b, out);
    (void)in_sizes; (void)n_in; (void)out_size; (void)ws_size;
}